// Round 1
// baseline (467.883 us; speedup 1.0000x reference)
//
#include <hip/hip_runtime.h>
#include <math.h>

typedef unsigned short u16;
typedef short s16x8 __attribute__((ext_vector_type(8)));
typedef float f32x4 __attribute__((ext_vector_type(4)));
typedef u16 u16x4 __attribute__((ext_vector_type(4)));

// ---------------- workspace layout (bytes) ----------------
// XB   : x bf16 [4096][2048]                16,777,216   (reused as QH [16][4096][128])
// WQKV : eff qkv weights bf16 [3072][2048]  12,582,912
// WP   : eff proj weights bf16 [2048][2048]  8,388,608
// QKV  : fp32 [4096][3072]                  50,331,648   (first 16.8MB reused as Y bf16 [4096][2048])
// KH   : bf16 [4][4096][128]                 4,194,304
// VT   : bf16 [4][128][4096]                 4,194,304
static constexpr size_t OFF_XB   = 0;
static constexpr size_t OFF_WQKV = 16777216;
static constexpr size_t OFF_WP   = 29360128;
static constexpr size_t OFF_QKV  = 37748736;
static constexpr size_t OFF_KH   = 88080384;
static constexpr size_t OFF_VT   = 92274688;
// total 96,468,992 bytes

__device__ __forceinline__ u16 f2bf(float f) {
  union { float f; unsigned u; } v; v.f = f;
  unsigned r = v.u + 0x7fffu + ((v.u >> 16) & 1u);   // RNE
  return (u16)(r >> 16);
}

__device__ __forceinline__ void async16(const u16* g, u16* lds) {
  __builtin_amdgcn_global_load_lds(
      (const __attribute__((address_space(1))) void*)g,
      (__attribute__((address_space(3))) void*)lds, 16, 0, 0);
}

// ---------------- bitlinear weight quantization ----------------
// one block per row of 2048 cols
__global__ __launch_bounds__(256) void quant_rows(const float* __restrict__ W,
                                                  u16* __restrict__ out) {
  const int row = blockIdx.x, tid = threadIdx.x;
  const float* src = W + (size_t)row * 2048 + tid * 8;
  float4 a = *(const float4*)(src);
  float4 b = *(const float4*)(src + 4);
  float asum = fabsf(a.x)+fabsf(a.y)+fabsf(a.z)+fabsf(a.w)
             + fabsf(b.x)+fabsf(b.y)+fabsf(b.z)+fabsf(b.w);
  #pragma unroll
  for (int off = 1; off < 64; off <<= 1) asum += __shfl_xor(asum, off, 64);
  __shared__ float red[4];
  if ((tid & 63) == 0) red[tid >> 6] = asum;
  __syncthreads();
  float s = fmaxf((red[0]+red[1]+red[2]+red[3]) * (1.0f/2048.0f), 1e-5f);
  float v[8] = {a.x,a.y,a.z,a.w,b.x,b.y,b.z,b.w};
  u16* dst = out + (size_t)row * 2048 + tid * 8;
  #pragma unroll
  for (int i = 0; i < 8; i++) {
    float q = rintf(v[i] / s);              // IEEE div + RNE matches jnp.round(W/s)
    q = fminf(fmaxf(q, -1.f), 1.f);
    dst[i] = f2bf(q * s);
  }
}

// ---------------- fp32 -> bf16 ----------------
__global__ __launch_bounds__(256) void cvt_bf16(const float* __restrict__ in,
                                                u16* __restrict__ out) {
  size_t i = ((size_t)blockIdx.x * 256 + threadIdx.x) * 4;
  float4 v = *(const float4*)(in + i);
  u16x4 o;
  o.x = f2bf(v.x); o.y = f2bf(v.y); o.z = f2bf(v.z); o.w = f2bf(v.w);
  *(u16x4*)(out + i) = o;
}

// ---------------- GEMM  C[M][N] = A[M][K] * B[N][K]^T  (bf16 in, fp32 out) -------
// m97 structure: 128x128 tile, BK=32, global_load_lds w=16, 4 waves x (4x4 16x16x32 MFMA)
__global__ __launch_bounds__(256) void gemm_bt(const u16* __restrict__ A,
                                               const u16* __restrict__ B,
                                               float* __restrict__ C,
                                               int M, int N, int K) {
  __shared__ u16 sA[128 * 32];
  __shared__ u16 sB[128 * 32];
  const int tid = threadIdx.x;
  const int lane = tid & 63;
  const int wid = tid >> 6;
  const int lr = lane & 15, lq = lane >> 4;
  const int wm = (wid >> 1) * 64, wn = (wid & 1) * 64;
  const size_t m0 = (size_t)blockIdx.y * 128, n0 = (size_t)blockIdx.x * 128;

  const int r0 = tid >> 2, c0 = (tid & 3) * 8;
  const u16* Ab0 = A + (m0 + r0) * (size_t)K + c0;
  const u16* Ab1 = A + (m0 + 64 + r0) * (size_t)K + c0;
  const u16* Bb0 = B + (n0 + r0) * (size_t)K + c0;
  const u16* Bb1 = B + (n0 + 64 + r0) * (size_t)K + c0;
  u16* sA0 = &sA[tid * 8];
  u16* sA1 = &sA[(256 + tid) * 8];
  u16* sB0 = &sB[tid * 8];
  u16* sB1 = &sB[(256 + tid) * 8];

  f32x4 acc[4][4] = {};

  for (int kt = 0; kt < K; kt += 32) {
    async16(Ab0 + kt, sA0);
    async16(Ab1 + kt, sA1);
    async16(Bb0 + kt, sB0);
    async16(Bb1 + kt, sB1);
    __syncthreads();
    s16x8 af[4], bf[4];
    #pragma unroll
    for (int mt = 0; mt < 4; mt++)
      af[mt] = *(const s16x8*)&sA[(wm + mt * 16 + lr) * 32 + lq * 8];
    #pragma unroll
    for (int nt = 0; nt < 4; nt++)
      bf[nt] = *(const s16x8*)&sB[(wn + nt * 16 + lr) * 32 + lq * 8];
    #pragma unroll
    for (int mt = 0; mt < 4; mt++)
      #pragma unroll
      for (int nt = 0; nt < 4; nt++)
        acc[mt][nt] = __builtin_amdgcn_mfma_f32_16x16x32_bf16(af[mt], bf[nt], acc[mt][nt], 0, 0, 0);
    __syncthreads();
  }
  #pragma unroll
  for (int mt = 0; mt < 4; mt++)
    #pragma unroll
    for (int nt = 0; nt < 4; nt++)
      #pragma unroll
      for (int r = 0; r < 4; r++) {
        size_t m = m0 + wm + mt * 16 + lq * 4 + r;
        size_t n = n0 + wn + nt * 16 + lr;
        C[m * (size_t)N + n] = acc[mt][nt][r];
      }
}

// ---------------- rmsnorm + rope (+gain+scale for Q) ----------------
// grid (5, 4096), block 256 (4 waves); wave -> one (s, j) with j in 0..19
__global__ __launch_bounds__(256) void prep_qk(const float* __restrict__ qkv,
                                               const float* __restrict__ qgain,
                                               u16* __restrict__ Qh,
                                               u16* __restrict__ Kh) {
  const int s = blockIdx.y;
  const int j = blockIdx.x * 4 + (threadIdx.x >> 6);
  const int t = threadIdx.x & 63;
  const float* row = qkv + (size_t)s * 3072 + (size_t)j * 128;
  float x1 = row[t], x2 = row[t + 64];
  float ss = x1 * x1 + x2 * x2;
  #pragma unroll
  for (int off = 1; off < 64; off <<= 1) ss += __shfl_xor(ss, off, 64);
  float rn = rsqrtf(ss * (1.0f / 128.0f) + 1.1920929e-07f);
  float invf = exp2f(-(float)t * 0.20762050593048096f);  // log2(10000)/64
  float ang = (float)s * invf;
  float sn, c;
  sincosf(ang, &sn, &c);
  if (j < 16) {
    float g = qgain[j] * 0.12751738f;   // (1/sqrt(128)) * log2(e), folded for exp2 softmax
    float q1 = x1 * rn, q2 = x2 * rn;
    float o1 = (q1 * c + q2 * sn) * g;
    float o2 = (-q1 * sn + q2 * c) * g;
    u16* dst = Qh + ((size_t)j * 4096 + s) * 128;
    dst[t] = f2bf(o1); dst[t + 64] = f2bf(o2);
  } else {
    float k1 = x1 * rn, k2 = x2 * rn;
    float o1 = k1 * c + k2 * sn;
    float o2 = -k1 * sn + k2 * c;
    u16* dst = Kh + ((size_t)(j - 16) * 4096 + s) * 128;
    dst[t] = f2bf(o1); dst[t + 64] = f2bf(o2);
  }
}

// ---------------- V transpose: qkv[s][2560+c] -> Vt[c][s] bf16 ----------------
// grid (8, 64): 64(d) x 64(s) tiles
__global__ __launch_bounds__(256) void vtrans(const float* __restrict__ qkv,
                                              u16* __restrict__ Vtg) {
  __shared__ float tile[64][67];
  const int tid = threadIdx.x;
  const int s0 = blockIdx.y * 64;
  const int c0 = blockIdx.x * 64;
  #pragma unroll
  for (int it = 0; it < 4; it++) {
    int i = it * 256 + tid;
    int r = i >> 4, c = (i & 15) * 4;
    float4 v = *(const float4*)(qkv + (size_t)(s0 + r) * 3072 + 2560 + c0 + c);
    tile[r][c] = v.x; tile[r][c + 1] = v.y; tile[r][c + 2] = v.z; tile[r][c + 3] = v.w;
  }
  __syncthreads();
  #pragma unroll
  for (int it = 0; it < 2; it++) {
    int i = it * 256 + tid;
    int dl = i >> 3, sc = (i & 7) * 8;
    s16x8 ov;
    #pragma unroll
    for (int jj = 0; jj < 8; jj++) ov[jj] = (short)f2bf(tile[sc + jj][dl]);
    *(s16x8*)&Vtg[(size_t)(c0 + dl) * 4096 + s0 + sc] = ov;
  }
}

// ---------------- flash attention (causal, GQA 4:1) ----------------
// grid 1024 = 16 heads x 64 q-tiles (longest q-tiles first); block 256 = 4 waves
// wave owns 16 q rows; KV tiles of 64; online softmax in exp2 domain (scale folded in Q)
__global__ __launch_bounds__(256) void attn(const u16* __restrict__ Q,
                                            const u16* __restrict__ Kh,
                                            const u16* __restrict__ Vt,
                                            u16* __restrict__ Y) {
  const int h = blockIdx.x & 15;
  const int qt = 63 - (blockIdx.x >> 4);
  const int kvh = h >> 2;
  const int tid = threadIdx.x, lane = tid & 63, wid = tid >> 6;
  const int lr = lane & 15, lq = lane >> 4;

  __shared__ u16 sK[64][136];    // K tile [kv][d], padded
  __shared__ u16 sVt[128][72];   // V^T tile [d][kv], padded
  __shared__ u16 sP[4][16][72];  // per-wave P round-trip

  const int q0 = qt * 64;
  s16x8 qf[4];
  {
    const u16* qp = Q + ((size_t)h * 4096 + q0 + wid * 16 + lr) * 128 + lq * 8;
    #pragma unroll
    for (int kc = 0; kc < 4; kc++) qf[kc] = *(const s16x8*)(qp + kc * 32);
  }
  f32x4 oacc[8] = {};
  float mrow[4], lrow[4];
  #pragma unroll
  for (int r = 0; r < 4; r++) { mrow[r] = -1e30f; lrow[r] = 0.f; }

  const u16* Kbase = Kh + (size_t)kvh * 4096 * 128;
  const u16* Vbase = Vt + (size_t)kvh * 128 * 4096;

  for (int t = 0; t <= qt; ++t) {
    #pragma unroll
    for (int it = 0; it < 4; it++) {
      int idx = it * 256 + tid;
      int kr = idx >> 4, kc = (idx & 15) * 8;
      *(s16x8*)&sK[kr][kc] = *(const s16x8*)(Kbase + ((size_t)(t * 64 + kr)) * 128 + kc);
    }
    #pragma unroll
    for (int it = 0; it < 4; it++) {
      int idx = it * 256 + tid;
      int vd = idx >> 3, vc = (idx & 7) * 8;
      *(s16x8*)&sVt[vd][vc] = *(const s16x8*)(Vbase + (size_t)vd * 4096 + t * 64 + vc);
    }
    __syncthreads();

    // S = Q K^T (already scaled by 1/sqrt(128)*log2e via Q)
    f32x4 sacc[4] = {};
    #pragma unroll
    for (int nt = 0; nt < 4; nt++)
      #pragma unroll
      for (int kc = 0; kc < 4; kc++) {
        s16x8 kf = *(const s16x8*)&sK[nt * 16 + lr][kc * 32 + lq * 8];
        sacc[nt] = __builtin_amdgcn_mfma_f32_16x16x32_bf16(qf[kc], kf, sacc[nt], 0, 0, 0);
      }
    if (t == qt) {  // causal mask on diagonal tile
      #pragma unroll
      for (int nt = 0; nt < 4; nt++)
        #pragma unroll
        for (int r = 0; r < 4; r++)
          if (nt * 16 + lr > wid * 16 + lq * 4 + r) sacc[nt][r] = -1e30f;
    }
    // row max over the 16 lanes sharing lq
    float mx[4];
    #pragma unroll
    for (int r = 0; r < 4; r++)
      mx[r] = fmaxf(fmaxf(sacc[0][r], sacc[1][r]), fmaxf(sacc[2][r], sacc[3][r]));
    #pragma unroll
    for (int off = 1; off < 16; off <<= 1)
      #pragma unroll
      for (int r = 0; r < 4; r++) mx[r] = fmaxf(mx[r], __shfl_xor(mx[r], off, 64));
    float mnew[4], alpha[4], rsum[4];
    #pragma unroll
    for (int r = 0; r < 4; r++) {
      mnew[r] = fmaxf(mrow[r], mx[r]);
      alpha[r] = exp2f(mrow[r] - mnew[r]);
      rsum[r] = 0.f;
    }
    #pragma unroll
    for (int nt = 0; nt < 4; nt++)
      #pragma unroll
      for (int r = 0; r < 4; r++) {
        float p = exp2f(sacc[nt][r] - mnew[r]);
        rsum[r] += p;
        sP[wid][lq * 4 + r][nt * 16 + lr] = f2bf(p);
      }
    #pragma unroll
    for (int off = 1; off < 16; off <<= 1)
      #pragma unroll
      for (int r = 0; r < 4; r++) rsum[r] += __shfl_xor(rsum[r], off, 64);
    #pragma unroll
    for (int r = 0; r < 4; r++) { lrow[r] = lrow[r] * alpha[r] + rsum[r]; mrow[r] = mnew[r]; }
    #pragma unroll
    for (int dt = 0; dt < 8; dt++)
      #pragma unroll
      for (int r = 0; r < 4; r++) oacc[dt][r] *= alpha[r];
    // O += P V
    #pragma unroll
    for (int kc = 0; kc < 2; kc++) {
      s16x8 pf = *(const s16x8*)&sP[wid][lr][kc * 32 + lq * 8];
      #pragma unroll
      for (int dt = 0; dt < 8; dt++) {
        s16x8 vf = *(const s16x8*)&sVt[dt * 16 + lr][kc * 32 + lq * 8];
        oacc[dt] = __builtin_amdgcn_mfma_f32_16x16x32_bf16(pf, vf, oacc[dt], 0, 0, 0);
      }
    }
    __syncthreads();
  }
  float invl[4];
  #pragma unroll
  for (int r = 0; r < 4; r++) invl[r] = 1.0f / lrow[r];
  #pragma unroll
  for (int dt = 0; dt < 8; dt++)
    #pragma unroll
    for (int r = 0; r < 4; r++) {
      int qg = q0 + wid * 16 + lq * 4 + r;
      int d = dt * 16 + lr;
      Y[(size_t)qg * 2048 + h * 128 + d] = f2bf(oacc[dt][r] * invl[r]);
    }
}

// ---------------- launch ----------------
extern "C" void kernel_launch(void* const* d_in, const int* in_sizes, int n_in,
                              void* d_out, int out_size, void* d_ws, size_t ws_size,
                              hipStream_t stream) {
  const float* x  = (const float*)d_in[0];
  const float* wq = (const float*)d_in[1];
  const float* wk = (const float*)d_in[2];
  const float* wv = (const float*)d_in[3];
  const float* wp = (const float*)d_in[4];
  const float* qg = (const float*)d_in[5];
  float* out = (float*)d_out;
  char* ws = (char*)d_ws;

  u16*   XB   = (u16*)(ws + OFF_XB);
  u16*   WQKV = (u16*)(ws + OFF_WQKV);
  u16*   WP   = (u16*)(ws + OFF_WP);
  float* QKV  = (float*)(ws + OFF_QKV);
  u16*   QH   = XB;                    // reuse after GEMM1
  u16*   KH   = (u16*)(ws + OFF_KH);
  u16*   VT   = (u16*)(ws + OFF_VT);
  u16*   Yb   = (u16*)(ws + OFF_QKV);  // reuse after prep/vtrans

  quant_rows<<<2048, 256, 0, stream>>>(wq, WQKV);
  quant_rows<<<512,  256, 0, stream>>>(wk, WQKV + (size_t)2048 * 2048);
  quant_rows<<<512,  256, 0, stream>>>(wv, WQKV + (size_t)2560 * 2048);
  quant_rows<<<2048, 256, 0, stream>>>(wp, WP);
  cvt_bf16<<<8192, 256, 0, stream>>>(x, XB);
  gemm_bt<<<dim3(24, 32), 256, 0, stream>>>(XB, WQKV, QKV, 4096, 3072, 2048);
  prep_qk<<<dim3(5, 4096), 256, 0, stream>>>(QKV, qg, QH, KH);
  vtrans<<<dim3(8, 64), 256, 0, stream>>>(QKV, VT);
  attn<<<1024, 256, 0, stream>>>(QH, KH, VT, Yb);
  gemm_bt<<<dim3(16, 32), 256, 0, stream>>>(Yb, WP, out, 4096, 2048, 2048);
}

// Round 2
// 438.221 us; speedup vs baseline: 1.0677x; 1.0677x over previous
//
#include <hip/hip_runtime.h>
#include <math.h>

typedef unsigned short u16;
typedef short s16x8 __attribute__((ext_vector_type(8)));
typedef float f32x4 __attribute__((ext_vector_type(4)));
typedef u16 u16x4 __attribute__((ext_vector_type(4)));

// ---------------- workspace layout (bytes) ----------------
// XB   : x bf16 [4096][2048]                16,777,216   (reused as QH [16][4096][128])
// WQKV : eff qkv weights bf16 [3072][2048]  12,582,912   (reused as ML partials after gemm1)
// WP   : eff proj weights bf16 [2048][2048]  8,388,608
// QKV  : fp32 [4096][3072]                  50,331,648
//        first 16.8MB reused as Y bf16 [4096][2048]; remaining 33.5MB = O partials (512 x 64KB)
// KH   : bf16 [4][4096][128]                 4,194,304
// VT   : bf16 [4][128][4096]                 4,194,304
static constexpr size_t OFF_XB   = 0;
static constexpr size_t OFF_WQKV = 16777216;
static constexpr size_t OFF_WP   = 29360128;
static constexpr size_t OFF_QKV  = 37748736;
static constexpr size_t OFF_PART = 37748736 + 16777216;   // 54,525,952
static constexpr size_t OFF_KH   = 88080384;
static constexpr size_t OFF_VT   = 92274688;
// total 96,468,992 bytes

__device__ __forceinline__ u16 f2bf(float f) {
  union { float f; unsigned u; } v; v.f = f;
  unsigned r = v.u + 0x7fffu + ((v.u >> 16) & 1u);   // RNE
  return (u16)(r >> 16);
}

__device__ __forceinline__ void async16(const u16* g, u16* lds) {
  __builtin_amdgcn_global_load_lds(
      (const __attribute__((address_space(1))) void*)g,
      (__attribute__((address_space(3))) void*)lds, 16, 0, 0);
}

// ---------------- bitlinear weight quantization ----------------
__global__ __launch_bounds__(256) void quant_rows(const float* __restrict__ W,
                                                  u16* __restrict__ out) {
  const int row = blockIdx.x, tid = threadIdx.x;
  const float* src = W + (size_t)row * 2048 + tid * 8;
  float4 a = *(const float4*)(src);
  float4 b = *(const float4*)(src + 4);
  float asum = fabsf(a.x)+fabsf(a.y)+fabsf(a.z)+fabsf(a.w)
             + fabsf(b.x)+fabsf(b.y)+fabsf(b.z)+fabsf(b.w);
  #pragma unroll
  for (int off = 1; off < 64; off <<= 1) asum += __shfl_xor(asum, off, 64);
  __shared__ float red[4];
  if ((tid & 63) == 0) red[tid >> 6] = asum;
  __syncthreads();
  float s = fmaxf((red[0]+red[1]+red[2]+red[3]) * (1.0f/2048.0f), 1e-5f);
  float v[8] = {a.x,a.y,a.z,a.w,b.x,b.y,b.z,b.w};
  u16* dst = out + (size_t)row * 2048 + tid * 8;
  #pragma unroll
  for (int i = 0; i < 8; i++) {
    float q = rintf(v[i] / s);
    q = fminf(fmaxf(q, -1.f), 1.f);
    dst[i] = f2bf(q * s);
  }
}

// ---------------- fp32 -> bf16 ----------------
__global__ __launch_bounds__(256) void cvt_bf16(const float* __restrict__ in,
                                                u16* __restrict__ out) {
  size_t i = ((size_t)blockIdx.x * 256 + threadIdx.x) * 4;
  float4 v = *(const float4*)(in + i);
  u16x4 o;
  o.x = f2bf(v.x); o.y = f2bf(v.y); o.z = f2bf(v.z); o.w = f2bf(v.w);
  *(u16x4*)(out + i) = o;
}

// ---------------- GEMM  C[M][N] = A[M][K] * B[N][K]^T  (bf16 in, fp32 out) -------
__global__ __launch_bounds__(256) void gemm_bt(const u16* __restrict__ A,
                                               const u16* __restrict__ B,
                                               float* __restrict__ C,
                                               int M, int N, int K) {
  __shared__ u16 sA[128 * 32];
  __shared__ u16 sB[128 * 32];
  const int tid = threadIdx.x;
  const int lane = tid & 63;
  const int wid = tid >> 6;
  const int lr = lane & 15, lq = lane >> 4;
  const int wm = (wid >> 1) * 64, wn = (wid & 1) * 64;
  const size_t m0 = (size_t)blockIdx.y * 128, n0 = (size_t)blockIdx.x * 128;

  const int r0 = tid >> 2, c0 = (tid & 3) * 8;
  const u16* Ab0 = A + (m0 + r0) * (size_t)K + c0;
  const u16* Ab1 = A + (m0 + 64 + r0) * (size_t)K + c0;
  const u16* Bb0 = B + (n0 + r0) * (size_t)K + c0;
  const u16* Bb1 = B + (n0 + 64 + r0) * (size_t)K + c0;
  u16* sA0 = &sA[tid * 8];
  u16* sA1 = &sA[(256 + tid) * 8];
  u16* sB0 = &sB[tid * 8];
  u16* sB1 = &sB[(256 + tid) * 8];

  f32x4 acc[4][4] = {};

  for (int kt = 0; kt < K; kt += 32) {
    async16(Ab0 + kt, sA0);
    async16(Ab1 + kt, sA1);
    async16(Bb0 + kt, sB0);
    async16(Bb1 + kt, sB1);
    __syncthreads();
    s16x8 af[4], bf[4];
    #pragma unroll
    for (int mt = 0; mt < 4; mt++)
      af[mt] = *(const s16x8*)&sA[(wm + mt * 16 + lr) * 32 + lq * 8];
    #pragma unroll
    for (int nt = 0; nt < 4; nt++)
      bf[nt] = *(const s16x8*)&sB[(wn + nt * 16 + lr) * 32 + lq * 8];
    #pragma unroll
    for (int mt = 0; mt < 4; mt++)
      #pragma unroll
      for (int nt = 0; nt < 4; nt++)
        acc[mt][nt] = __builtin_amdgcn_mfma_f32_16x16x32_bf16(af[mt], bf[nt], acc[mt][nt], 0, 0, 0);
    __syncthreads();
  }
  #pragma unroll
  for (int mt = 0; mt < 4; mt++)
    #pragma unroll
    for (int nt = 0; nt < 4; nt++)
      #pragma unroll
      for (int r = 0; r < 4; r++) {
        size_t m = m0 + wm + mt * 16 + lq * 4 + r;
        size_t n = n0 + wn + nt * 16 + lr;
        C[m * (size_t)N + n] = acc[mt][nt][r];
      }
}

// ---------------- rmsnorm + rope (+gain+scale for Q) ----------------
__global__ __launch_bounds__(256) void prep_qk(const float* __restrict__ qkv,
                                               const float* __restrict__ qgain,
                                               u16* __restrict__ Qh,
                                               u16* __restrict__ Kh) {
  const int s = blockIdx.y;
  const int j = blockIdx.x * 4 + (threadIdx.x >> 6);
  const int t = threadIdx.x & 63;
  const float* row = qkv + (size_t)s * 3072 + (size_t)j * 128;
  float x1 = row[t], x2 = row[t + 64];
  float ss = x1 * x1 + x2 * x2;
  #pragma unroll
  for (int off = 1; off < 64; off <<= 1) ss += __shfl_xor(ss, off, 64);
  float rn = rsqrtf(ss * (1.0f / 128.0f) + 1.1920929e-07f);
  float invf = exp2f(-(float)t * 0.20762050593048096f);  // log2(10000)/64
  float ang = (float)s * invf;
  float sn, c;
  sincosf(ang, &sn, &c);
  if (j < 16) {
    float g = qgain[j] * 0.12751738f;   // (1/sqrt(128)) * log2(e)
    float q1 = x1 * rn, q2 = x2 * rn;
    float o1 = (q1 * c + q2 * sn) * g;
    float o2 = (-q1 * sn + q2 * c) * g;
    u16* dst = Qh + ((size_t)j * 4096 + s) * 128;
    dst[t] = f2bf(o1); dst[t + 64] = f2bf(o2);
  } else {
    float k1 = x1 * rn, k2 = x2 * rn;
    float o1 = k1 * c + k2 * sn;
    float o2 = -k1 * sn + k2 * c;
    u16* dst = Kh + ((size_t)(j - 16) * 4096 + s) * 128;
    dst[t] = f2bf(o1); dst[t + 64] = f2bf(o2);
  }
}

// ---------------- V transpose ----------------
__global__ __launch_bounds__(256) void vtrans(const float* __restrict__ qkv,
                                              u16* __restrict__ Vtg) {
  __shared__ float tile[64][67];
  const int tid = threadIdx.x;
  const int s0 = blockIdx.y * 64;
  const int c0 = blockIdx.x * 64;
  #pragma unroll
  for (int it = 0; it < 4; it++) {
    int i = it * 256 + tid;
    int r = i >> 4, c = (i & 15) * 4;
    float4 v = *(const float4*)(qkv + (size_t)(s0 + r) * 3072 + 2560 + c0 + c);
    tile[r][c] = v.x; tile[r][c + 1] = v.y; tile[r][c + 2] = v.z; tile[r][c + 3] = v.w;
  }
  __syncthreads();
  #pragma unroll
  for (int it = 0; it < 2; it++) {
    int i = it * 256 + tid;
    int dl = i >> 3, sc = (i & 7) * 8;
    s16x8 ov;
    #pragma unroll
    for (int jj = 0; jj < 8; jj++) ov[jj] = (short)f2bf(tile[sc + jj][dl]);
    *(s16x8*)&Vtg[(size_t)(c0 + dl) * 4096 + s0 + sc] = ov;
  }
}

// ---------------- flash attention (causal, GQA 4:1), balanced + kv-split ------
// 768 blocks, 4 waves x 32 q-rows (128-row q-tiles). Work units sorted
// descending by kv-tile count into blockIdx order:
//   qt in 16..31: 2 chunks of (qt+1) kv-tiles each -> fp32 partials (O,m,l)
//   qt in  0..15: single unit, 2qt+2 kv-tiles      -> writes Y directly
// l computed via ones-row MFMA (sVt row 128); alpha-rescale skipped when the
// running max doesn't grow; P stored truncated-bf16.
__global__ __launch_bounds__(256, 2) void attn(const u16* __restrict__ Q,
                                               const u16* __restrict__ Kh,
                                               const u16* __restrict__ Vt,
                                               u16* __restrict__ Y,
                                               float* __restrict__ Opart,
                                               float* __restrict__ MLpart) {
  const int tid = threadIdx.x, lane = tid & 63, wid = tid >> 6;
  const int lr = lane & 15, lq = lane >> 4;

  // blockIdx -> (qt, chunk, h, split) in descending-cost order
  int rem = blockIdx.x, s = 32;
  for (;;) {
    int cnt = (s >= 17 ? 32 : 0) + (((s & 1) == 0) ? 16 : 0);
    if (rem < cnt) break;
    rem -= cnt; --s;
  }
  int qt, chunk, h, split;
  if (s >= 17 && rem < 32) { split = 1; qt = s - 1; chunk = rem >> 4; h = rem & 15; }
  else { split = 0; if (s >= 17) rem -= 32; qt = (s >> 1) - 1; chunk = 0; h = rem & 15; }
  const int t0 = split ? chunk * (qt + 1) : 0;
  const int t1 = split ? t0 + qt + 1 : 2 * qt + 2;
  const int kvh = h >> 2;
  const int qbase = qt * 128;

  __shared__ u16 sK[64][136];
  __shared__ u16 sVt[144][72];   // rows 128..143: ones row + zeros (l trick)
  __shared__ u16 sP[4][32][72];

  // preset ones-row block (re-done every launch; ws is poisoned)
  for (int i = tid; i < 16 * 72; i += 256) {
    int r = i / 72, c = i - r * 72;
    sVt[128 + r][c] = (r == 0) ? (u16)0x3F80 : (u16)0;
  }

  s16x8 qf[2][4];
  #pragma unroll
  for (int f = 0; f < 2; f++) {
    const u16* qp = Q + ((size_t)h * 4096 + qbase + wid * 32 + f * 16 + lr) * 128 + lq * 8;
    #pragma unroll
    for (int kc = 0; kc < 4; kc++) qf[f][kc] = *(const s16x8*)(qp + kc * 32);
  }

  f32x4 oacc[2][9] = {};
  float mrow[2][4];
  #pragma unroll
  for (int f = 0; f < 2; f++)
    #pragma unroll
    for (int r = 0; r < 4; r++) mrow[f][r] = -1e30f;

  const u16* Kbase = Kh + (size_t)kvh * 4096 * 128;
  const u16* Vbase = Vt + (size_t)kvh * 128 * 4096;

  for (int t = t0; t < t1; ++t) {
    #pragma unroll
    for (int it = 0; it < 4; it++) {
      int idx = it * 256 + tid;
      int kr = idx >> 4, kc8 = (idx & 15) * 8;
      *(s16x8*)&sK[kr][kc8] = *(const s16x8*)(Kbase + (size_t)(t * 64 + kr) * 128 + kc8);
    }
    #pragma unroll
    for (int it = 0; it < 4; it++) {
      int idx = it * 256 + tid;
      int vd = idx >> 3, vc = (idx & 7) * 8;
      *(s16x8*)&sVt[vd][vc] = *(const s16x8*)(Vbase + (size_t)vd * 4096 + t * 64 + vc);
    }
    __syncthreads();

    f32x4 sacc[2][4] = {};
    #pragma unroll
    for (int nt = 0; nt < 4; nt++)
      #pragma unroll
      for (int kc = 0; kc < 4; kc++) {
        s16x8 kf = *(const s16x8*)&sK[nt * 16 + lr][kc * 32 + lq * 8];
        sacc[0][nt] = __builtin_amdgcn_mfma_f32_16x16x32_bf16(qf[0][kc], kf, sacc[0][nt], 0, 0, 0);
        sacc[1][nt] = __builtin_amdgcn_mfma_f32_16x16x32_bf16(qf[1][kc], kf, sacc[1][nt], 0, 0, 0);
      }

    if (t >= 2 * qt) {   // causal mask (diagonal-adjacent tiles only)
      #pragma unroll
      for (int f = 0; f < 2; f++) {
        int qr0 = qbase + wid * 32 + f * 16 + lq * 4;
        #pragma unroll
        for (int nt = 0; nt < 4; nt++) {
          int col = t * 64 + nt * 16 + lr;
          #pragma unroll
          for (int r = 0; r < 4; r++)
            if (col > qr0 + r) sacc[f][nt][r] = -1e30f;
        }
      }
    }

    float mx[2][4];
    #pragma unroll
    for (int f = 0; f < 2; f++)
      #pragma unroll
      for (int r = 0; r < 4; r++)
        mx[f][r] = fmaxf(fmaxf(sacc[f][0][r], sacc[f][1][r]),
                         fmaxf(sacc[f][2][r], sacc[f][3][r]));
    #pragma unroll
    for (int off = 1; off < 16; off <<= 1)
      #pragma unroll
      for (int f = 0; f < 2; f++)
        #pragma unroll
        for (int r = 0; r < 4; r++) mx[f][r] = fmaxf(mx[f][r], __shfl_xor(mx[f][r], off, 64));

    bool grow = false;
    #pragma unroll
    for (int f = 0; f < 2; f++)
      #pragma unroll
      for (int r = 0; r < 4; r++) grow = grow || (mx[f][r] > mrow[f][r]);
    if (__any(grow)) {
      float al[2][4];
      #pragma unroll
      for (int f = 0; f < 2; f++)
        #pragma unroll
        for (int r = 0; r < 4; r++) {
          float mn = fmaxf(mrow[f][r], mx[f][r]);
          al[f][r] = exp2f(mrow[f][r] - mn);
          mrow[f][r] = mn;
        }
      #pragma unroll
      for (int f = 0; f < 2; f++)
        #pragma unroll
        for (int dt = 0; dt < 9; dt++)
          #pragma unroll
          for (int r = 0; r < 4; r++) oacc[f][dt][r] *= al[f][r];
    }

    #pragma unroll
    for (int f = 0; f < 2; f++)
      #pragma unroll
      for (int nt = 0; nt < 4; nt++)
        #pragma unroll
        for (int r = 0; r < 4; r++) {
          union { float fv; unsigned u; } pu;
          pu.fv = exp2f(sacc[f][nt][r] - mrow[f][r]);
          sP[wid][f * 16 + lq * 4 + r][nt * 16 + lr] = (u16)(pu.u >> 16);  // trunc bf16
        }

    #pragma unroll
    for (int kc = 0; kc < 2; kc++) {
      s16x8 pf0 = *(const s16x8*)&sP[wid][lr][kc * 32 + lq * 8];
      s16x8 pf1 = *(const s16x8*)&sP[wid][16 + lr][kc * 32 + lq * 8];
      #pragma unroll
      for (int dt = 0; dt < 9; dt++) {
        s16x8 vf = *(const s16x8*)&sVt[dt * 16 + lr][kc * 32 + lq * 8];
        oacc[0][dt] = __builtin_amdgcn_mfma_f32_16x16x32_bf16(pf0, vf, oacc[0][dt], 0, 0, 0);
        oacc[1][dt] = __builtin_amdgcn_mfma_f32_16x16x32_bf16(pf1, vf, oacc[1][dt], 0, 0, 0);
      }
    }
    __syncthreads();
  }

  if (split) {
    const int pidx = ((qt - 16) * 16 + h) * 2 + chunk;
    float* Op = Opart + (size_t)pidx * 16384;
    #pragma unroll
    for (int f = 0; f < 2; f++)
      #pragma unroll
      for (int dt = 0; dt < 8; dt++)
        #pragma unroll
        for (int r = 0; r < 4; r++)
          Op[(wid * 32 + f * 16 + lq * 4 + r) * 128 + dt * 16 + lr] = oacc[f][dt][r];
    if (lr == 0) {
      #pragma unroll
      for (int f = 0; f < 2; f++)
        #pragma unroll
        for (int r = 0; r < 4; r++) {
          int row = wid * 32 + f * 16 + lq * 4 + r;
          MLpart[(size_t)pidx * 256 + row * 2]     = mrow[f][r];
          MLpart[(size_t)pidx * 256 + row * 2 + 1] = oacc[f][8][r];
        }
    }
  } else {
    #pragma unroll
    for (int f = 0; f < 2; f++) {
      float linv[4];
      #pragma unroll
      for (int r = 0; r < 4; r++) {
        float lv = __shfl(oacc[f][8][r], lane & 48);  // broadcast from lr==0
        linv[r] = 1.0f / lv;
      }
      #pragma unroll
      for (int dt = 0; dt < 8; dt++)
        #pragma unroll
        for (int r = 0; r < 4; r++) {
          int q = qbase + wid * 32 + f * 16 + lq * 4 + r;
          Y[(size_t)q * 2048 + h * 128 + dt * 16 + lr] = f2bf(oacc[f][dt][r] * linv[r]);
        }
    }
  }
}

// ---------------- combine kv-split partials ----------------
// 256 blocks = (qt16, h); merges 2 chunks -> Y rows
__global__ __launch_bounds__(256) void combine(const float* __restrict__ Op,
                                               const float* __restrict__ ML,
                                               u16* __restrict__ Y) {
  const int blk = blockIdx.x;
  const int qt16 = blk >> 4, h = blk & 15;
  const int p0 = blk * 2, p1 = p0 + 1;
  const int tid = threadIdx.x;
  const int row = tid >> 1, half = (tid & 1) * 64;
  float m0 = ML[(size_t)p0 * 256 + row * 2], l0 = ML[(size_t)p0 * 256 + row * 2 + 1];
  float m1 = ML[(size_t)p1 * 256 + row * 2], l1 = ML[(size_t)p1 * 256 + row * 2 + 1];
  float m = fmaxf(m0, m1);
  float w0 = exp2f(m0 - m), w1 = exp2f(m1 - m);
  float inv = 1.0f / (l0 * w0 + l1 * w1);
  w0 *= inv; w1 *= inv;
  const float* o0 = Op + (size_t)p0 * 16384 + row * 128 + half;
  const float* o1 = Op + (size_t)p1 * 16384 + row * 128 + half;
  size_t q = (size_t)(qt16 + 16) * 128 + row;
  u16* dst = Y + q * 2048 + h * 128 + half;
  #pragma unroll
  for (int c = 0; c < 64; c += 8) {
    float4 a0 = *(const float4*)(o0 + c), b0 = *(const float4*)(o0 + c + 4);
    float4 a1 = *(const float4*)(o1 + c), b1 = *(const float4*)(o1 + c + 4);
    u16 tmp[8];
    tmp[0] = f2bf(a0.x * w0 + a1.x * w1);
    tmp[1] = f2bf(a0.y * w0 + a1.y * w1);
    tmp[2] = f2bf(a0.z * w0 + a1.z * w1);
    tmp[3] = f2bf(a0.w * w0 + a1.w * w1);
    tmp[4] = f2bf(b0.x * w0 + b1.x * w1);
    tmp[5] = f2bf(b0.y * w0 + b1.y * w1);
    tmp[6] = f2bf(b0.z * w0 + b1.z * w1);
    tmp[7] = f2bf(b0.w * w0 + b1.w * w1);
    *(s16x8*)(dst + c) = *(s16x8*)tmp;
  }
}

// ---------------- launch ----------------
extern "C" void kernel_launch(void* const* d_in, const int* in_sizes, int n_in,
                              void* d_out, int out_size, void* d_ws, size_t ws_size,
                              hipStream_t stream) {
  const float* x  = (const float*)d_in[0];
  const float* wq = (const float*)d_in[1];
  const float* wk = (const float*)d_in[2];
  const float* wv = (const float*)d_in[3];
  const float* wp = (const float*)d_in[4];
  const float* qg = (const float*)d_in[5];
  float* out = (float*)d_out;
  char* ws = (char*)d_ws;

  u16*   XB    = (u16*)(ws + OFF_XB);
  u16*   WQKV  = (u16*)(ws + OFF_WQKV);
  u16*   WP    = (u16*)(ws + OFF_WP);
  float* QKV   = (float*)(ws + OFF_QKV);
  u16*   QH    = XB;                      // reuse after GEMM1
  u16*   KH    = (u16*)(ws + OFF_KH);
  u16*   VT    = (u16*)(ws + OFF_VT);
  u16*   Yb    = (u16*)(ws + OFF_QKV);    // reuse after prep/vtrans
  float* OPART = (float*)(ws + OFF_PART);
  float* MLP   = (float*)(ws + OFF_WQKV); // reuse after GEMM1

  quant_rows<<<2048, 256, 0, stream>>>(wq, WQKV);
  quant_rows<<<512,  256, 0, stream>>>(wk, WQKV + (size_t)2048 * 2048);
  quant_rows<<<512,  256, 0, stream>>>(wv, WQKV + (size_t)2560 * 2048);
  quant_rows<<<2048, 256, 0, stream>>>(wp, WP);
  cvt_bf16<<<8192, 256, 0, stream>>>(x, XB);
  gemm_bt<<<dim3(24, 32), 256, 0, stream>>>(XB, WQKV, QKV, 4096, 3072, 2048);
  prep_qk<<<dim3(5, 4096), 256, 0, stream>>>(QKV, qg, QH, KH);
  vtrans<<<dim3(8, 64), 256, 0, stream>>>(QKV, VT);
  attn<<<768, 256, 0, stream>>>(QH, KH, VT, Yb, OPART, MLP);
  combine<<<256, 256, 0, stream>>>(OPART, MLP, Yb);
  gemm_bt<<<dim3(16, 32), 256, 0, stream>>>(Yb, WP, out, 4096, 2048, 2048);
}

// Round 3
// 430.188 us; speedup vs baseline: 1.0876x; 1.0187x over previous
//
#include <hip/hip_runtime.h>
#include <math.h>

typedef unsigned short u16;
typedef short s16x8 __attribute__((ext_vector_type(8)));
typedef short s16x4 __attribute__((ext_vector_type(4)));
typedef float f32x4 __attribute__((ext_vector_type(4)));
typedef u16 u16x4 __attribute__((ext_vector_type(4)));

// ---------------- workspace layout (bytes) ----------------
static constexpr size_t OFF_XB   = 0;
static constexpr size_t OFF_WQKV = 16777216;
static constexpr size_t OFF_WP   = 29360128;
static constexpr size_t OFF_QKV  = 37748736;
static constexpr size_t OFF_PART = 37748736 + 16777216;   // 54,525,952
static constexpr size_t OFF_KH   = 88080384;
static constexpr size_t OFF_VT   = 92274688;
// total 96,468,992 bytes

__device__ __forceinline__ u16 f2bf(float f) {
  union { float f; unsigned u; } v; v.f = f;
  unsigned r = v.u + 0x7fffu + ((v.u >> 16) & 1u);   // RNE
  return (u16)(r >> 16);
}

__device__ __forceinline__ void async16(const u16* g, u16* lds) {
  __builtin_amdgcn_global_load_lds(
      (const __attribute__((address_space(1))) void*)g,
      (__attribute__((address_space(3))) void*)lds, 16, 0, 0);
}

// ---------------- bitlinear weight quantization ----------------
__global__ __launch_bounds__(256) void quant_rows(const float* __restrict__ W,
                                                  u16* __restrict__ out) {
  const int row = blockIdx.x, tid = threadIdx.x;
  const float* src = W + (size_t)row * 2048 + tid * 8;
  float4 a = *(const float4*)(src);
  float4 b = *(const float4*)(src + 4);
  float asum = fabsf(a.x)+fabsf(a.y)+fabsf(a.z)+fabsf(a.w)
             + fabsf(b.x)+fabsf(b.y)+fabsf(b.z)+fabsf(b.w);
  #pragma unroll
  for (int off = 1; off < 64; off <<= 1) asum += __shfl_xor(asum, off, 64);
  __shared__ float red[4];
  if ((tid & 63) == 0) red[tid >> 6] = asum;
  __syncthreads();
  float s = fmaxf((red[0]+red[1]+red[2]+red[3]) * (1.0f/2048.0f), 1e-5f);
  float v[8] = {a.x,a.y,a.z,a.w,b.x,b.y,b.z,b.w};
  u16* dst = out + (size_t)row * 2048 + tid * 8;
  #pragma unroll
  for (int i = 0; i < 8; i++) {
    float q = rintf(v[i] / s);
    q = fminf(fmaxf(q, -1.f), 1.f);
    dst[i] = f2bf(q * s);
  }
}

// ---------------- fp32 -> bf16 ----------------
__global__ __launch_bounds__(256) void cvt_bf16(const float* __restrict__ in,
                                                u16* __restrict__ out) {
  size_t i = ((size_t)blockIdx.x * 256 + threadIdx.x) * 4;
  float4 v = *(const float4*)(in + i);
  u16x4 o;
  o.x = f2bf(v.x); o.y = f2bf(v.y); o.z = f2bf(v.z); o.w = f2bf(v.w);
  *(u16x4*)(out + i) = o;
}

// ---------------- GEMM  C[M][N] = A[M][K] * B[N][K]^T  (bf16 in, fp32 out) -------
__global__ __launch_bounds__(256) void gemm_bt(const u16* __restrict__ A,
                                               const u16* __restrict__ B,
                                               float* __restrict__ C,
                                               int M, int N, int K) {
  __shared__ u16 sA[128 * 32];
  __shared__ u16 sB[128 * 32];
  const int tid = threadIdx.x;
  const int lane = tid & 63;
  const int wid = tid >> 6;
  const int lr = lane & 15, lq = lane >> 4;
  const int wm = (wid >> 1) * 64, wn = (wid & 1) * 64;
  const size_t m0 = (size_t)blockIdx.y * 128, n0 = (size_t)blockIdx.x * 128;

  const int r0 = tid >> 2, c0 = (tid & 3) * 8;
  const u16* Ab0 = A + (m0 + r0) * (size_t)K + c0;
  const u16* Ab1 = A + (m0 + 64 + r0) * (size_t)K + c0;
  const u16* Bb0 = B + (n0 + r0) * (size_t)K + c0;
  const u16* Bb1 = B + (n0 + 64 + r0) * (size_t)K + c0;
  u16* sA0 = &sA[tid * 8];
  u16* sA1 = &sA[(256 + tid) * 8];
  u16* sB0 = &sB[tid * 8];
  u16* sB1 = &sB[(256 + tid) * 8];

  f32x4 acc[4][4] = {};

  for (int kt = 0; kt < K; kt += 32) {
    async16(Ab0 + kt, sA0);
    async16(Ab1 + kt, sA1);
    async16(Bb0 + kt, sB0);
    async16(Bb1 + kt, sB1);
    __syncthreads();
    s16x8 af[4], bf[4];
    #pragma unroll
    for (int mt = 0; mt < 4; mt++)
      af[mt] = *(const s16x8*)&sA[(wm + mt * 16 + lr) * 32 + lq * 8];
    #pragma unroll
    for (int nt = 0; nt < 4; nt++)
      bf[nt] = *(const s16x8*)&sB[(wn + nt * 16 + lr) * 32 + lq * 8];
    #pragma unroll
    for (int mt = 0; mt < 4; mt++)
      #pragma unroll
      for (int nt = 0; nt < 4; nt++)
        acc[mt][nt] = __builtin_amdgcn_mfma_f32_16x16x32_bf16(af[mt], bf[nt], acc[mt][nt], 0, 0, 0);
    __syncthreads();
  }
  #pragma unroll
  for (int mt = 0; mt < 4; mt++)
    #pragma unroll
    for (int nt = 0; nt < 4; nt++)
      #pragma unroll
      for (int r = 0; r < 4; r++) {
        size_t m = m0 + wm + mt * 16 + lq * 4 + r;
        size_t n = n0 + wn + nt * 16 + lr;
        C[m * (size_t)N + n] = acc[mt][nt][r];
      }
}

// ---------------- rmsnorm + rope (+gain+scale for Q) ----------------
__global__ __launch_bounds__(256) void prep_qk(const float* __restrict__ qkv,
                                               const float* __restrict__ qgain,
                                               u16* __restrict__ Qh,
                                               u16* __restrict__ Kh) {
  const int s = blockIdx.y;
  const int j = blockIdx.x * 4 + (threadIdx.x >> 6);
  const int t = threadIdx.x & 63;
  const float* row = qkv + (size_t)s * 3072 + (size_t)j * 128;
  float x1 = row[t], x2 = row[t + 64];
  float ss = x1 * x1 + x2 * x2;
  #pragma unroll
  for (int off = 1; off < 64; off <<= 1) ss += __shfl_xor(ss, off, 64);
  float rn = rsqrtf(ss * (1.0f / 128.0f) + 1.1920929e-07f);
  float invf = exp2f(-(float)t * 0.20762050593048096f);  // log2(10000)/64
  float ang = (float)s * invf;
  float sn, c;
  sincosf(ang, &sn, &c);
  if (j < 16) {
    float g = qgain[j] * 0.12751738f;   // (1/sqrt(128)) * log2(e)
    float q1 = x1 * rn, q2 = x2 * rn;
    float o1 = (q1 * c + q2 * sn) * g;
    float o2 = (-q1 * sn + q2 * c) * g;
    u16* dst = Qh + ((size_t)j * 4096 + s) * 128;
    dst[t] = f2bf(o1); dst[t + 64] = f2bf(o2);
  } else {
    float k1 = x1 * rn, k2 = x2 * rn;
    float o1 = k1 * c + k2 * sn;
    float o2 = -k1 * sn + k2 * c;
    u16* dst = Kh + ((size_t)(j - 16) * 4096 + s) * 128;
    dst[t] = f2bf(o1); dst[t + 64] = f2bf(o2);
  }
}

// ---------------- V transpose ----------------
__global__ __launch_bounds__(256) void vtrans(const float* __restrict__ qkv,
                                              u16* __restrict__ Vtg) {
  __shared__ float tile[64][67];
  const int tid = threadIdx.x;
  const int s0 = blockIdx.y * 64;
  const int c0 = blockIdx.x * 64;
  #pragma unroll
  for (int it = 0; it < 4; it++) {
    int i = it * 256 + tid;
    int r = i >> 4, c = (i & 15) * 4;
    float4 v = *(const float4*)(qkv + (size_t)(s0 + r) * 3072 + 2560 + c0 + c);
    tile[r][c] = v.x; tile[r][c + 1] = v.y; tile[r][c + 2] = v.z; tile[r][c + 3] = v.w;
  }
  __syncthreads();
  #pragma unroll
  for (int it = 0; it < 2; it++) {
    int i = it * 256 + tid;
    int dl = i >> 3, sc = (i & 7) * 8;
    s16x8 ov;
    #pragma unroll
    for (int jj = 0; jj < 8; jj++) ov[jj] = (short)f2bf(tile[sc + jj][dl]);
    *(s16x8*)&Vtg[(size_t)(c0 + dl) * 4096 + s0 + sc] = ov;
  }
}

// ---------------- flash attention v3: S^T form, P stays in registers ---------
// S^T = K·Q^T via 16x16x32 (C-layout of S^T == B-layout of 16x16x16 MFMA).
// O^T += V^T·P^T via 16x16x16; l via ones-row; no sP, no LDS P round-trip.
// 768 blocks, 4 waves x 32 q-rows; same balance/kv-split machinery as before.
__global__ __launch_bounds__(256, 2) void attn(const u16* __restrict__ Q,
                                               const u16* __restrict__ Kh,
                                               const u16* __restrict__ Vt,
                                               u16* __restrict__ Y,
                                               float* __restrict__ Opart,
                                               float* __restrict__ MLpart) {
  const int tid = threadIdx.x, lane = tid & 63, wid = tid >> 6;
  const int lr = lane & 15, lq = lane >> 4;

  // blockIdx -> (qt, chunk, h, split) in descending-cost order
  int rem = blockIdx.x, s = 32;
  for (;;) {
    int cnt = (s >= 17 ? 32 : 0) + (((s & 1) == 0) ? 16 : 0);
    if (rem < cnt) break;
    rem -= cnt; --s;
  }
  int qt, chunk, h, split;
  if (s >= 17 && rem < 32) { split = 1; qt = s - 1; chunk = rem >> 4; h = rem & 15; }
  else { split = 0; if (s >= 17) rem -= 32; qt = (s >> 1) - 1; chunk = 0; h = rem & 15; }
  const int t0 = split ? chunk * (qt + 1) : 0;
  const int t1 = split ? t0 + qt + 1 : 2 * qt + 2;
  const int kvh = h >> 2;
  const int qbase = qt * 128;

  __shared__ u16 sK[64][136];    // K tile [kv][d]
  __shared__ u16 sVt[144][72];   // V^T tile [d][kv'], kv' = lq*16+nt*4+r; rows 128..143 = ones-row block

  // ones-row block (l trick)
  for (int i = tid; i < 16 * 72; i += 256) {
    int r = i / 72, c = i - r * 72;
    sVt[128 + r][c] = (r == 0) ? (u16)0x3F80 : (u16)0;
  }

  // Q as B-operand frags: lane holds Q[q = base+f*16+lr][kc*32 + lq*8 + j]
  s16x8 qf[2][4];
  #pragma unroll
  for (int f = 0; f < 2; f++) {
    const u16* qp = Q + ((size_t)h * 4096 + qbase + wid * 32 + f * 16 + lr) * 128 + lq * 8;
    #pragma unroll
    for (int kc = 0; kc < 4; kc++) qf[f][kc] = *(const s16x8*)(qp + kc * 32);
  }

  f32x4 oacc[2][9] = {};      // O^T frags: [f][dt], dt=8 is l (ones row)
  float mrow[2] = {-1e30f, -1e30f};

  const u16* Kbase = Kh + (size_t)kvh * 4096 * 128;
  const u16* Vbase = Vt + (size_t)kvh * 128 * 4096;

  for (int t = t0; t < t1; ++t) {
    #pragma unroll
    for (int it = 0; it < 4; it++) {
      int idx = it * 256 + tid;
      int kr = idx >> 4, kc8 = (idx & 15) * 8;
      *(s16x8*)&sK[kr][kc8] = *(const s16x8*)(Kbase + (size_t)(t * 64 + kr) * 128 + kc8);
    }
    #pragma unroll
    for (int it = 0; it < 4; it++) {
      int idx = it * 256 + tid;
      int vd = idx >> 3, vc = (idx & 7) * 8;   // vc multiple of 8
      s16x8 v = *(const s16x8*)(Vbase + (size_t)vd * 4096 + t * 64 + vc);
      // permuted store: kv -> col' = ((kv>>2)&3)*16 + (kv>>4)*4 + (kv&3)
      int g0 = ((vc >> 2) & 3) * 16 + (vc >> 4) * 4;
      int g1 = ((((vc >> 2) & 3) + 1)) * 16 + (vc >> 4) * 4;
      s16x4 lo = {v[0], v[1], v[2], v[3]};
      s16x4 hi = {v[4], v[5], v[6], v[7]};
      *(s16x4*)&sVt[vd][g0] = lo;
      *(s16x4*)&sVt[vd][g1] = hi;
    }
    __syncthreads();

    // S^T = K · Q^T : A = K-frag (m=kv), B = Q-frag (n=q)
    f32x4 sacc[2][4] = {};
    #pragma unroll
    for (int nt = 0; nt < 4; nt++)
      #pragma unroll
      for (int kc = 0; kc < 4; kc++) {
        s16x8 kf = *(const s16x8*)&sK[nt * 16 + lr][kc * 32 + lq * 8];
        sacc[0][nt] = __builtin_amdgcn_mfma_f32_16x16x32_bf16(kf, qf[0][kc], sacc[0][nt], 0, 0, 0);
        sacc[1][nt] = __builtin_amdgcn_mfma_f32_16x16x32_bf16(kf, qf[1][kc], sacc[1][nt], 0, 0, 0);
      }

    if (t >= 2 * qt) {   // causal mask: kv_g > q_g
      #pragma unroll
      for (int f = 0; f < 2; f++) {
        int qg = qbase + wid * 32 + f * 16 + lr;
        #pragma unroll
        for (int nt = 0; nt < 4; nt++) {
          int kv0 = t * 64 + nt * 16 + lq * 4;
          #pragma unroll
          for (int r = 0; r < 4; r++)
            if (kv0 + r > qg) sacc[f][nt][r] = -1e30f;
        }
      }
    }

    // per-lane max over 16 in-reg values, then across lq (lanes xor 16,32)
    float mx[2];
    #pragma unroll
    for (int f = 0; f < 2; f++) {
      float m01 = fmaxf(fmaxf(sacc[f][0][0], sacc[f][0][1]), fmaxf(sacc[f][0][2], sacc[f][0][3]));
      float m23 = fmaxf(fmaxf(sacc[f][1][0], sacc[f][1][1]), fmaxf(sacc[f][1][2], sacc[f][1][3]));
      float m45 = fmaxf(fmaxf(sacc[f][2][0], sacc[f][2][1]), fmaxf(sacc[f][2][2], sacc[f][2][3]));
      float m67 = fmaxf(fmaxf(sacc[f][3][0], sacc[f][3][1]), fmaxf(sacc[f][3][2], sacc[f][3][3]));
      mx[f] = fmaxf(fmaxf(m01, m23), fmaxf(m45, m67));
      mx[f] = fmaxf(mx[f], __shfl_xor(mx[f], 16, 64));
      mx[f] = fmaxf(mx[f], __shfl_xor(mx[f], 32, 64));
    }

    bool grow = (mx[0] > mrow[0]) || (mx[1] > mrow[1]);
    if (__any(grow)) {
      #pragma unroll
      for (int f = 0; f < 2; f++) {
        float mn = fmaxf(mrow[f], mx[f]);
        float al = exp2f(mrow[f] - mn);
        mrow[f] = mn;
        #pragma unroll
        for (int dt = 0; dt < 9; dt++)
          #pragma unroll
          for (int r = 0; r < 4; r++) oacc[f][dt][r] *= al;
      }
    }

    // P^T = exp2(S^T - m), packed to bf16 in-register (trunc)
    s16x4 pf[2][4];
    #pragma unroll
    for (int f = 0; f < 2; f++)
      #pragma unroll
      for (int nt = 0; nt < 4; nt++)
        #pragma unroll
        for (int r = 0; r < 4; r++) {
          union { float fv; unsigned u; } pu;
          pu.fv = exp2f(sacc[f][nt][r] - mrow[f]);
          pf[f][nt][r] = (short)(pu.u >> 16);
        }

    // O^T += V^T · P^T  (A = V^T frag, B = P^T frag, 16x16x16)
    #pragma unroll
    for (int dt = 0; dt < 9; dt++) {
      s16x8 v01 = *(const s16x8*)&sVt[dt * 16 + lr][lq * 16];
      s16x8 v23 = *(const s16x8*)&sVt[dt * 16 + lr][lq * 16 + 8];
      s16x4 vf0 = {v01[0], v01[1], v01[2], v01[3]};
      s16x4 vf1 = {v01[4], v01[5], v01[6], v01[7]};
      s16x4 vf2 = {v23[0], v23[1], v23[2], v23[3]};
      s16x4 vf3 = {v23[4], v23[5], v23[6], v23[7]};
      #pragma unroll
      for (int f = 0; f < 2; f++) {
        oacc[f][dt] = __builtin_amdgcn_mfma_f32_16x16x16bf16_1k(vf0, pf[f][0], oacc[f][dt], 0, 0, 0);
        oacc[f][dt] = __builtin_amdgcn_mfma_f32_16x16x16bf16_1k(vf1, pf[f][1], oacc[f][dt], 0, 0, 0);
        oacc[f][dt] = __builtin_amdgcn_mfma_f32_16x16x16bf16_1k(vf2, pf[f][2], oacc[f][dt], 0, 0, 0);
        oacc[f][dt] = __builtin_amdgcn_mfma_f32_16x16x16bf16_1k(vf3, pf[f][3], oacc[f][dt], 0, 0, 0);
      }
    }
    __syncthreads();
  }

  // O^T layout per lane: q = base + f*16 + lr ; d = dt*16 + lq*4 + r
  if (split) {
    const int pidx = ((qt - 16) * 16 + h) * 2 + chunk;
    float* Op = Opart + (size_t)pidx * 16384;
    #pragma unroll
    for (int f = 0; f < 2; f++) {
      int row = wid * 32 + f * 16 + lr;
      #pragma unroll
      for (int dt = 0; dt < 8; dt++)
        *(f32x4*)&Op[row * 128 + dt * 16 + lq * 4] = oacc[f][dt];
    }
    if (lq == 0) {
      #pragma unroll
      for (int f = 0; f < 2; f++) {
        int row = wid * 32 + f * 16 + lr;
        MLpart[(size_t)pidx * 256 + row * 2]     = mrow[f];
        MLpart[(size_t)pidx * 256 + row * 2 + 1] = oacc[f][8][0];
      }
    }
  } else {
    #pragma unroll
    for (int f = 0; f < 2; f++) {
      float lv = __shfl(oacc[f][8][0], lr, 64);   // l for q=lr lives in lane lr (lq==0), reg 0
      float linv = 1.0f / lv;
      int qg = qbase + wid * 32 + f * 16 + lr;
      #pragma unroll
      for (int dt = 0; dt < 8; dt++) {
        u16 tmp[4];
        #pragma unroll
        for (int r = 0; r < 4; r++) tmp[r] = f2bf(oacc[f][dt][r] * linv);
        *(s16x4*)&Y[(size_t)qg * 2048 + h * 128 + dt * 16 + lq * 4] = *(s16x4*)tmp;
      }
    }
  }
}

// ---------------- combine kv-split partials ----------------
__global__ __launch_bounds__(256) void combine(const float* __restrict__ Op,
                                               const float* __restrict__ ML,
                                               u16* __restrict__ Y) {
  const int blk = blockIdx.x;
  const int qt16 = blk >> 4, h = blk & 15;
  const int p0 = blk * 2, p1 = p0 + 1;
  const int tid = threadIdx.x;
  const int row = tid >> 1, half = (tid & 1) * 64;
  float m0 = ML[(size_t)p0 * 256 + row * 2], l0 = ML[(size_t)p0 * 256 + row * 2 + 1];
  float m1 = ML[(size_t)p1 * 256 + row * 2], l1 = ML[(size_t)p1 * 256 + row * 2 + 1];
  float m = fmaxf(m0, m1);
  float w0 = exp2f(m0 - m), w1 = exp2f(m1 - m);
  float inv = 1.0f / (l0 * w0 + l1 * w1);
  w0 *= inv; w1 *= inv;
  const float* o0 = Op + (size_t)p0 * 16384 + row * 128 + half;
  const float* o1 = Op + (size_t)p1 * 16384 + row * 128 + half;
  size_t q = (size_t)(qt16 + 16) * 128 + row;
  u16* dst = Y + q * 2048 + h * 128 + half;
  #pragma unroll
  for (int c = 0; c < 64; c += 8) {
    float4 a0 = *(const float4*)(o0 + c), b0 = *(const float4*)(o0 + c + 4);
    float4 a1 = *(const float4*)(o1 + c), b1 = *(const float4*)(o1 + c + 4);
    u16 tmp[8];
    tmp[0] = f2bf(a0.x * w0 + a1.x * w1);
    tmp[1] = f2bf(a0.y * w0 + a1.y * w1);
    tmp[2] = f2bf(a0.z * w0 + a1.z * w1);
    tmp[3] = f2bf(a0.w * w0 + a1.w * w1);
    tmp[4] = f2bf(b0.x * w0 + b1.x * w1);
    tmp[5] = f2bf(b0.y * w0 + b1.y * w1);
    tmp[6] = f2bf(b0.z * w0 + b1.z * w1);
    tmp[7] = f2bf(b0.w * w0 + b1.w * w1);
    *(s16x8*)(dst + c) = *(s16x8*)tmp;
  }
}

// ---------------- launch ----------------
extern "C" void kernel_launch(void* const* d_in, const int* in_sizes, int n_in,
                              void* d_out, int out_size, void* d_ws, size_t ws_size,
                              hipStream_t stream) {
  const float* x  = (const float*)d_in[0];
  const float* wq = (const float*)d_in[1];
  const float* wk = (const float*)d_in[2];
  const float* wv = (const float*)d_in[3];
  const float* wp = (const float*)d_in[4];
  const float* qg = (const float*)d_in[5];
  float* out = (float*)d_out;
  char* ws = (char*)d_ws;

  u16*   XB    = (u16*)(ws + OFF_XB);
  u16*   WQKV  = (u16*)(ws + OFF_WQKV);
  u16*   WP    = (u16*)(ws + OFF_WP);
  float* QKV   = (float*)(ws + OFF_QKV);
  u16*   QH    = XB;                      // reuse after GEMM1
  u16*   KH    = (u16*)(ws + OFF_KH);
  u16*   VT    = (u16*)(ws + OFF_VT);
  u16*   Yb    = (u16*)(ws + OFF_QKV);    // reuse after prep/vtrans
  float* OPART = (float*)(ws + OFF_PART);
  float* MLP   = (float*)(ws + OFF_WQKV); // reuse after GEMM1

  quant_rows<<<2048, 256, 0, stream>>>(wq, WQKV);
  quant_rows<<<512,  256, 0, stream>>>(wk, WQKV + (size_t)2048 * 2048);
  quant_rows<<<512,  256, 0, stream>>>(wv, WQKV + (size_t)2560 * 2048);
  quant_rows<<<2048, 256, 0, stream>>>(wp, WP);
  cvt_bf16<<<8192, 256, 0, stream>>>(x, XB);
  gemm_bt<<<dim3(24, 32), 256, 0, stream>>>(XB, WQKV, QKV, 4096, 3072, 2048);
  prep_qk<<<dim3(5, 4096), 256, 0, stream>>>(QKV, qg, QH, KH);
  vtrans<<<dim3(8, 64), 256, 0, stream>>>(QKV, VT);
  attn<<<768, 256, 0, stream>>>(QH, KH, VT, Yb, OPART, MLP);
  combine<<<256, 256, 0, stream>>>(OPART, MLP, Yb);
  gemm_bt<<<dim3(16, 32), 256, 0, stream>>>(Yb, WP, out, 4096, 2048, 2048);
}

// Round 4
// 419.878 us; speedup vs baseline: 1.1143x; 1.0246x over previous
//
#include <hip/hip_runtime.h>
#include <math.h>

typedef unsigned short u16;
typedef short s16x8 __attribute__((ext_vector_type(8)));
typedef short s16x4 __attribute__((ext_vector_type(4)));
typedef float f32x4 __attribute__((ext_vector_type(4)));
typedef u16 u16x4 __attribute__((ext_vector_type(4)));

// ---------------- workspace layout (bytes) ----------------
// XB   : x bf16 [4096][2048]                16,777,216   (reused as QH [16][4096][128])
// WQKV : eff qkv weights bf16 [3072][2048]  12,582,912   (reused as ML partials [1024][128][2] f32 = 1 MB)
// WP   : eff proj weights bf16 [2048][2048]  8,388,608
// QKV  : fp32 [4096][3072]                  50,331,648
//        reused after prep/vtrans as: Opart bf16 [1024][128][128] = 33,554,432
//                                     Y bf16 [4096][2048]         = 16,777,216  (exact fit)
// KH   : bf16 [4][4096][128]                 4,194,304
// VT   : bf16 [4][128][4096]                 4,194,304
static constexpr size_t OFF_XB   = 0;
static constexpr size_t OFF_WQKV = 16777216;
static constexpr size_t OFF_WP   = 29360128;
static constexpr size_t OFF_QKV  = 37748736;
static constexpr size_t OFF_Y    = 37748736 + 33554432;   // 71,303,168
static constexpr size_t OFF_KH   = 88080384;
static constexpr size_t OFF_VT   = 92274688;
// total 96,468,992 bytes

__device__ __forceinline__ u16 f2bf(float f) {
  union { float f; unsigned u; } v; v.f = f;
  unsigned r = v.u + 0x7fffu + ((v.u >> 16) & 1u);   // RNE
  return (u16)(r >> 16);
}

__device__ __forceinline__ float bf2f(u16 b) {
  union { unsigned u; float f; } v; v.u = ((unsigned)b) << 16;
  return v.f;
}

__device__ __forceinline__ void async16(const u16* g, u16* lds) {
  __builtin_amdgcn_global_load_lds(
      (const __attribute__((address_space(1))) void*)g,
      (__attribute__((address_space(3))) void*)lds, 16, 0, 0);
}

// ---------------- bitlinear weight quantization ----------------
__global__ __launch_bounds__(256) void quant_rows(const float* __restrict__ W,
                                                  u16* __restrict__ out) {
  const int row = blockIdx.x, tid = threadIdx.x;
  const float* src = W + (size_t)row * 2048 + tid * 8;
  float4 a = *(const float4*)(src);
  float4 b = *(const float4*)(src + 4);
  float asum = fabsf(a.x)+fabsf(a.y)+fabsf(a.z)+fabsf(a.w)
             + fabsf(b.x)+fabsf(b.y)+fabsf(b.z)+fabsf(b.w);
  #pragma unroll
  for (int off = 1; off < 64; off <<= 1) asum += __shfl_xor(asum, off, 64);
  __shared__ float red[4];
  if ((tid & 63) == 0) red[tid >> 6] = asum;
  __syncthreads();
  float s = fmaxf((red[0]+red[1]+red[2]+red[3]) * (1.0f/2048.0f), 1e-5f);
  float v[8] = {a.x,a.y,a.z,a.w,b.x,b.y,b.z,b.w};
  u16* dst = out + (size_t)row * 2048 + tid * 8;
  #pragma unroll
  for (int i = 0; i < 8; i++) {
    float q = rintf(v[i] / s);
    q = fminf(fmaxf(q, -1.f), 1.f);
    dst[i] = f2bf(q * s);
  }
}

// ---------------- fp32 -> bf16 ----------------
__global__ __launch_bounds__(256) void cvt_bf16(const float* __restrict__ in,
                                                u16* __restrict__ out) {
  size_t i = ((size_t)blockIdx.x * 256 + threadIdx.x) * 4;
  float4 v = *(const float4*)(in + i);
  u16x4 o;
  o.x = f2bf(v.x); o.y = f2bf(v.y); o.z = f2bf(v.z); o.w = f2bf(v.w);
  *(u16x4*)(out + i) = o;
}

// ---------------- GEMM  C[M][N] = A[M][K] * B[N][K]^T  (bf16 in, fp32 out) -------
__global__ __launch_bounds__(256) void gemm_bt(const u16* __restrict__ A,
                                               const u16* __restrict__ B,
                                               float* __restrict__ C,
                                               int M, int N, int K) {
  __shared__ u16 sA[128 * 32];
  __shared__ u16 sB[128 * 32];
  const int tid = threadIdx.x;
  const int lane = tid & 63;
  const int wid = tid >> 6;
  const int lr = lane & 15, lq = lane >> 4;
  const int wm = (wid >> 1) * 64, wn = (wid & 1) * 64;
  const size_t m0 = (size_t)blockIdx.y * 128, n0 = (size_t)blockIdx.x * 128;

  const int r0 = tid >> 2, c0 = (tid & 3) * 8;
  const u16* Ab0 = A + (m0 + r0) * (size_t)K + c0;
  const u16* Ab1 = A + (m0 + 64 + r0) * (size_t)K + c0;
  const u16* Bb0 = B + (n0 + r0) * (size_t)K + c0;
  const u16* Bb1 = B + (n0 + 64 + r0) * (size_t)K + c0;
  u16* sA0 = &sA[tid * 8];
  u16* sA1 = &sA[(256 + tid) * 8];
  u16* sB0 = &sB[tid * 8];
  u16* sB1 = &sB[(256 + tid) * 8];

  f32x4 acc[4][4] = {};

  for (int kt = 0; kt < K; kt += 32) {
    async16(Ab0 + kt, sA0);
    async16(Ab1 + kt, sA1);
    async16(Bb0 + kt, sB0);
    async16(Bb1 + kt, sB1);
    __syncthreads();
    s16x8 af[4], bf[4];
    #pragma unroll
    for (int mt = 0; mt < 4; mt++)
      af[mt] = *(const s16x8*)&sA[(wm + mt * 16 + lr) * 32 + lq * 8];
    #pragma unroll
    for (int nt = 0; nt < 4; nt++)
      bf[nt] = *(const s16x8*)&sB[(wn + nt * 16 + lr) * 32 + lq * 8];
    #pragma unroll
    for (int mt = 0; mt < 4; mt++)
      #pragma unroll
      for (int nt = 0; nt < 4; nt++)
        acc[mt][nt] = __builtin_amdgcn_mfma_f32_16x16x32_bf16(af[mt], bf[nt], acc[mt][nt], 0, 0, 0);
    __syncthreads();
  }
  #pragma unroll
  for (int mt = 0; mt < 4; mt++)
    #pragma unroll
    for (int nt = 0; nt < 4; nt++)
      #pragma unroll
      for (int r = 0; r < 4; r++) {
        size_t m = m0 + wm + mt * 16 + lq * 4 + r;
        size_t n = n0 + wn + nt * 16 + lr;
        C[m * (size_t)N + n] = acc[mt][nt][r];
      }
}

// ---------------- rmsnorm + rope (+gain+scale for Q) ----------------
__global__ __launch_bounds__(256) void prep_qk(const float* __restrict__ qkv,
                                               const float* __restrict__ qgain,
                                               u16* __restrict__ Qh,
                                               u16* __restrict__ Kh) {
  const int s = blockIdx.y;
  const int j = blockIdx.x * 4 + (threadIdx.x >> 6);
  const int t = threadIdx.x & 63;
  const float* row = qkv + (size_t)s * 3072 + (size_t)j * 128;
  float x1 = row[t], x2 = row[t + 64];
  float ss = x1 * x1 + x2 * x2;
  #pragma unroll
  for (int off = 1; off < 64; off <<= 1) ss += __shfl_xor(ss, off, 64);
  float rn = rsqrtf(ss * (1.0f / 128.0f) + 1.1920929e-07f);
  float invf = exp2f(-(float)t * 0.20762050593048096f);  // log2(10000)/64
  float ang = (float)s * invf;
  float sn, c;
  sincosf(ang, &sn, &c);
  if (j < 16) {
    float g = qgain[j] * 0.12751738f;   // (1/sqrt(128)) * log2(e)
    float q1 = x1 * rn, q2 = x2 * rn;
    float o1 = (q1 * c + q2 * sn) * g;
    float o2 = (-q1 * sn + q2 * c) * g;
    u16* dst = Qh + ((size_t)j * 4096 + s) * 128;
    dst[t] = f2bf(o1); dst[t + 64] = f2bf(o2);
  } else {
    float k1 = x1 * rn, k2 = x2 * rn;
    float o1 = k1 * c + k2 * sn;
    float o2 = -k1 * sn + k2 * c;
    u16* dst = Kh + ((size_t)(j - 16) * 4096 + s) * 128;
    dst[t] = f2bf(o1); dst[t + 64] = f2bf(o2);
  }
}

// ---------------- V transpose ----------------
__global__ __launch_bounds__(256) void vtrans(const float* __restrict__ qkv,
                                              u16* __restrict__ Vtg) {
  __shared__ float tile[64][67];
  const int tid = threadIdx.x;
  const int s0 = blockIdx.y * 64;
  const int c0 = blockIdx.x * 64;
  #pragma unroll
  for (int it = 0; it < 4; it++) {
    int i = it * 256 + tid;
    int r = i >> 4, c = (i & 15) * 4;
    float4 v = *(const float4*)(qkv + (size_t)(s0 + r) * 3072 + 2560 + c0 + c);
    tile[r][c] = v.x; tile[r][c + 1] = v.y; tile[r][c + 2] = v.z; tile[r][c + 3] = v.w;
  }
  __syncthreads();
  #pragma unroll
  for (int it = 0; it < 2; it++) {
    int i = it * 256 + tid;
    int dl = i >> 3, sc = (i & 7) * 8;
    s16x8 ov;
    #pragma unroll
    for (int jj = 0; jj < 8; jj++) ov[jj] = (short)f2bf(tile[sc + jj][dl]);
    *(s16x8*)&Vtg[(size_t)(c0 + dl) * 4096 + s0 + sc] = ov;
  }
}

// ---------------- flash attention v4: uniform kv-split, all-partial ----------
// Grid 1024 = 16 h x 32 qt x 2 chunks. Unit (h, qt, chunk) covers q-tile
// [qt*128, qt*128+128) x kv-tiles [chunk*(qt+1), (chunk+1)*(qt+1)).
// Decoded biggest-first: p=b>>4, qt=31-(p>>1). All units write bf16 O-partial
// + fp32 (m,l); combine merges the 2 chunks. S^T form; P in registers; l via
// VALU reduce. LDS 35,840 B -> 4 blocks/CU.
__global__ __launch_bounds__(256, 2) void attn(const u16* __restrict__ Q,
                                               const u16* __restrict__ Kh,
                                               const u16* __restrict__ Vt,
                                               u16* __restrict__ Opart,
                                               float* __restrict__ MLpart) {
  const int tid = threadIdx.x, lane = tid & 63, wid = tid >> 6;
  const int lr = lane & 15, lq = lane >> 4;

  const int b = blockIdx.x;
  const int h = b & 15;
  const int p = b >> 4;
  const int qt = 31 - (p >> 1);
  const int chunk = p & 1;
  const int t0 = chunk * (qt + 1);
  const int t1 = t0 + qt + 1;
  const int kvh = h >> 2;
  const int qbase = qt * 128;

  __shared__ u16 sK[64][136];    // K tile [kv][d], padded
  __shared__ u16 sVt[128][72];   // V^T tile [d][kv'], kv' permuted for x16 A-frags

  // Q as B-operand frags: lane holds Q[q = qbase+wid*32+f*16+lr][kc*32+lq*8+j]
  s16x8 qf[2][4];
  #pragma unroll
  for (int f = 0; f < 2; f++) {
    const u16* qp = Q + ((size_t)h * 4096 + qbase + wid * 32 + f * 16 + lr) * 128 + lq * 8;
    #pragma unroll
    for (int kc = 0; kc < 4; kc++) qf[f][kc] = *(const s16x8*)(qp + kc * 32);
  }

  f32x4 oacc[2][8] = {};            // O^T frags
  float mrow[2] = {-1e30f, -1e30f};
  float lrow[2] = {0.f, 0.f};

  const u16* Kbase = Kh + (size_t)kvh * 4096 * 128;
  const u16* Vbase = Vt + (size_t)kvh * 128 * 4096;

  for (int t = t0; t < t1; ++t) {
    #pragma unroll
    for (int it = 0; it < 4; it++) {
      int idx = it * 256 + tid;
      int kr = idx >> 4, kc8 = (idx & 15) * 8;
      *(s16x8*)&sK[kr][kc8] = *(const s16x8*)(Kbase + (size_t)(t * 64 + kr) * 128 + kc8);
    }
    #pragma unroll
    for (int it = 0; it < 4; it++) {
      int idx = it * 256 + tid;
      int vd = idx >> 3, vc = (idx & 7) * 8;
      s16x8 v = *(const s16x8*)(Vbase + (size_t)vd * 4096 + t * 64 + vc);
      // permuted: kv -> col' = ((kv>>2)&3)*16 + (kv>>4)*4 + (kv&3)
      int g0 = ((vc >> 2) & 3) * 16 + (vc >> 4) * 4;
      int g1 = (((vc >> 2) & 3) + 1) * 16 + (vc >> 4) * 4;
      s16x4 lo = {v[0], v[1], v[2], v[3]};
      s16x4 hi = {v[4], v[5], v[6], v[7]};
      *(s16x4*)&sVt[vd][g0] = lo;
      *(s16x4*)&sVt[vd][g1] = hi;
    }
    __syncthreads();

    // S^T = K · Q^T
    f32x4 sacc[2][4] = {};
    #pragma unroll
    for (int nt = 0; nt < 4; nt++)
      #pragma unroll
      for (int kc = 0; kc < 4; kc++) {
        s16x8 kf = *(const s16x8*)&sK[nt * 16 + lr][kc * 32 + lq * 8];
        sacc[0][nt] = __builtin_amdgcn_mfma_f32_16x16x32_bf16(kf, qf[0][kc], sacc[0][nt], 0, 0, 0);
        sacc[1][nt] = __builtin_amdgcn_mfma_f32_16x16x32_bf16(kf, qf[1][kc], sacc[1][nt], 0, 0, 0);
      }

    if (t >= 2 * qt) {   // causal mask: kv > q
      #pragma unroll
      for (int f = 0; f < 2; f++) {
        int qg = qbase + wid * 32 + f * 16 + lr;
        #pragma unroll
        for (int nt = 0; nt < 4; nt++) {
          int kv0 = t * 64 + nt * 16 + lq * 4;
          #pragma unroll
          for (int r = 0; r < 4; r++)
            if (kv0 + r > qg) sacc[f][nt][r] = -1e30f;
        }
      }
    }

    // row max: 16 in-reg + lanes xor 16,32
    float mx[2];
    #pragma unroll
    for (int f = 0; f < 2; f++) {
      float m01 = fmaxf(fmaxf(sacc[f][0][0], sacc[f][0][1]), fmaxf(sacc[f][0][2], sacc[f][0][3]));
      float m23 = fmaxf(fmaxf(sacc[f][1][0], sacc[f][1][1]), fmaxf(sacc[f][1][2], sacc[f][1][3]));
      float m45 = fmaxf(fmaxf(sacc[f][2][0], sacc[f][2][1]), fmaxf(sacc[f][2][2], sacc[f][2][3]));
      float m67 = fmaxf(fmaxf(sacc[f][3][0], sacc[f][3][1]), fmaxf(sacc[f][3][2], sacc[f][3][3]));
      mx[f] = fmaxf(fmaxf(m01, m23), fmaxf(m45, m67));
      mx[f] = fmaxf(mx[f], __shfl_xor(mx[f], 16, 64));
      mx[f] = fmaxf(mx[f], __shfl_xor(mx[f], 32, 64));
    }

    bool grow = (mx[0] > mrow[0]) || (mx[1] > mrow[1]);
    if (__any(grow)) {
      #pragma unroll
      for (int f = 0; f < 2; f++) {
        float mn = fmaxf(mrow[f], mx[f]);
        float al = exp2f(mrow[f] - mn);
        mrow[f] = mn;
        lrow[f] *= al;
        #pragma unroll
        for (int dt = 0; dt < 8; dt++)
          #pragma unroll
          for (int r = 0; r < 4; r++) oacc[f][dt][r] *= al;
      }
    }

    // P^T = exp2(S^T - m): pack bf16 (trunc) + VALU row-sum for l
    s16x4 pf[2][4];
    float rsum[2] = {0.f, 0.f};
    #pragma unroll
    for (int f = 0; f < 2; f++)
      #pragma unroll
      for (int nt = 0; nt < 4; nt++)
        #pragma unroll
        for (int r = 0; r < 4; r++) {
          union { float fv; unsigned u; } pu;
          pu.fv = exp2f(sacc[f][nt][r] - mrow[f]);
          rsum[f] += pu.fv;
          pf[f][nt][r] = (short)(pu.u >> 16);
        }
    #pragma unroll
    for (int f = 0; f < 2; f++) {
      rsum[f] += __shfl_xor(rsum[f], 16, 64);
      rsum[f] += __shfl_xor(rsum[f], 32, 64);
      lrow[f] += rsum[f];
    }

    // O^T += V^T · P^T  (16x16x16)
    #pragma unroll
    for (int dt = 0; dt < 8; dt++) {
      s16x8 v01 = *(const s16x8*)&sVt[dt * 16 + lr][lq * 16];
      s16x8 v23 = *(const s16x8*)&sVt[dt * 16 + lr][lq * 16 + 8];
      s16x4 vf0 = {v01[0], v01[1], v01[2], v01[3]};
      s16x4 vf1 = {v01[4], v01[5], v01[6], v01[7]};
      s16x4 vf2 = {v23[0], v23[1], v23[2], v23[3]};
      s16x4 vf3 = {v23[4], v23[5], v23[6], v23[7]};
      #pragma unroll
      for (int f = 0; f < 2; f++) {
        oacc[f][dt] = __builtin_amdgcn_mfma_f32_16x16x16bf16_1k(vf0, pf[f][0], oacc[f][dt], 0, 0, 0);
        oacc[f][dt] = __builtin_amdgcn_mfma_f32_16x16x16bf16_1k(vf1, pf[f][1], oacc[f][dt], 0, 0, 0);
        oacc[f][dt] = __builtin_amdgcn_mfma_f32_16x16x16bf16_1k(vf2, pf[f][2], oacc[f][dt], 0, 0, 0);
        oacc[f][dt] = __builtin_amdgcn_mfma_f32_16x16x16bf16_1k(vf3, pf[f][3], oacc[f][dt], 0, 0, 0);
      }
    }
    __syncthreads();
  }

  // write bf16 O-partial + fp32 (m,l).  O^T lane layout: q=f*16+lr, d=dt*16+lq*4+r
  u16* Op = Opart + (size_t)b * 16384;
  #pragma unroll
  for (int f = 0; f < 2; f++) {
    int row = wid * 32 + f * 16 + lr;
    #pragma unroll
    for (int dt = 0; dt < 8; dt++) {
      u16 tmp[4];
      #pragma unroll
      for (int r = 0; r < 4; r++) tmp[r] = f2bf(oacc[f][dt][r]);
      *(s16x4*)&Op[row * 128 + dt * 16 + lq * 4] = *(s16x4*)tmp;
    }
  }
  if (lq == 0) {
    #pragma unroll
    for (int f = 0; f < 2; f++) {
      int row = wid * 32 + f * 16 + lr;
      MLpart[(size_t)b * 256 + row * 2]     = mrow[f];
      MLpart[(size_t)b * 256 + row * 2 + 1] = lrow[f];
    }
  }
}

// ---------------- combine: merge the 2 chunks of each (qt,h) -> Y ----------
// 512 blocks; attn unit indices: b = p*16+h, p = (31-qt)*2 + chunk
__global__ __launch_bounds__(256) void combine(const u16* __restrict__ Op,
                                               const float* __restrict__ ML,
                                               u16* __restrict__ Y) {
  const int blk = blockIdx.x;
  const int qtc = blk >> 4, h = blk & 15;
  const int qt = 31 - qtc;
  const int b0 = (qtc * 2) * 16 + h, b1 = b0 + 16;
  const int tid = threadIdx.x;
  const int row = tid >> 1, half = (tid & 1) * 64;
  float m0 = ML[(size_t)b0 * 256 + row * 2], l0 = ML[(size_t)b0 * 256 + row * 2 + 1];
  float m1 = ML[(size_t)b1 * 256 + row * 2], l1 = ML[(size_t)b1 * 256 + row * 2 + 1];
  float m = fmaxf(m0, m1);
  float w0 = exp2f(m0 - m), w1 = exp2f(m1 - m);
  float inv = 1.0f / (l0 * w0 + l1 * w1);
  w0 *= inv; w1 *= inv;
  const u16* o0 = Op + (size_t)b0 * 16384 + row * 128 + half;
  const u16* o1 = Op + (size_t)b1 * 16384 + row * 128 + half;
  size_t q = (size_t)qt * 128 + row;
  u16* dst = Y + q * 2048 + h * 128 + half;
  #pragma unroll
  for (int c = 0; c < 64; c += 8) {
    s16x8 a0 = *(const s16x8*)(o0 + c);
    s16x8 a1 = *(const s16x8*)(o1 + c);
    u16 tmp[8];
    #pragma unroll
    for (int jj = 0; jj < 8; jj++)
      tmp[jj] = f2bf(bf2f((u16)a0[jj]) * w0 + bf2f((u16)a1[jj]) * w1);
    *(s16x8*)(dst + c) = *(s16x8*)tmp;
  }
}

// ---------------- launch ----------------
extern "C" void kernel_launch(void* const* d_in, const int* in_sizes, int n_in,
                              void* d_out, int out_size, void* d_ws, size_t ws_size,
                              hipStream_t stream) {
  const float* x  = (const float*)d_in[0];
  const float* wq = (const float*)d_in[1];
  const float* wk = (const float*)d_in[2];
  const float* wv = (const float*)d_in[3];
  const float* wp = (const float*)d_in[4];
  const float* qg = (const float*)d_in[5];
  float* out = (float*)d_out;
  char* ws = (char*)d_ws;

  u16*   XB    = (u16*)(ws + OFF_XB);
  u16*   WQKV  = (u16*)(ws + OFF_WQKV);
  u16*   WP    = (u16*)(ws + OFF_WP);
  float* QKV   = (float*)(ws + OFF_QKV);
  u16*   QH    = XB;                      // reuse after GEMM1
  u16*   KH    = (u16*)(ws + OFF_KH);
  u16*   VT    = (u16*)(ws + OFF_VT);
  u16*   OPART = (u16*)(ws + OFF_QKV);    // reuse after prep/vtrans
  u16*   Yb    = (u16*)(ws + OFF_Y);
  float* MLP   = (float*)(ws + OFF_WQKV); // reuse after GEMM1

  quant_rows<<<2048, 256, 0, stream>>>(wq, WQKV);
  quant_rows<<<512,  256, 0, stream>>>(wk, WQKV + (size_t)2048 * 2048);
  quant_rows<<<512,  256, 0, stream>>>(wv, WQKV + (size_t)2560 * 2048);
  quant_rows<<<2048, 256, 0, stream>>>(wp, WP);
  cvt_bf16<<<8192, 256, 0, stream>>>(x, XB);
  gemm_bt<<<dim3(24, 32), 256, 0, stream>>>(XB, WQKV, QKV, 4096, 3072, 2048);
  prep_qk<<<dim3(5, 4096), 256, 0, stream>>>(QKV, qg, QH, KH);
  vtrans<<<dim3(8, 64), 256, 0, stream>>>(QKV, VT);
  attn<<<1024, 256, 0, stream>>>(QH, KH, VT, OPART, MLP);
  combine<<<512, 256, 0, stream>>>(OPART, MLP, Yb);
  gemm_bt<<<dim3(16, 32), 256, 0, stream>>>(Yb, WP, out, 4096, 2048, 2048);
}

// Round 5
// 418.084 us; speedup vs baseline: 1.1191x; 1.0043x over previous
//
#include <hip/hip_runtime.h>
#include <math.h>

typedef unsigned short u16;
typedef short s16x8 __attribute__((ext_vector_type(8)));
typedef short s16x4 __attribute__((ext_vector_type(4)));
typedef float f32x4 __attribute__((ext_vector_type(4)));
typedef u16 u16x4 __attribute__((ext_vector_type(4)));

// ---------------- workspace layout (bytes) ----------------
// XB   : x bf16 [4096][2048]               16,777,216  (reused as QH [16][4096][128])
// WQKV : qkv weights bf16 [3072][2048]     12,582,912  (region reused after gemm1:
//          KH bf16 [4][4096][128] @ +0, VT bf16 [4][128][4096] @ +4,194,304,
//          ML f32 [16*79][128][2] @ +8,388,608 (1,294,336 B))
// WP   : proj weights bf16 [2048][2048]     8,388,608
// QKV  : fp32 [4096][3072]                 50,331,648  (reused: Opart bf16 1264x[128][128] = 41,418,752)
// Y    : bf16 [4096][2048] @ 79,691,776    16,777,216  (ends 96,468,992)
static constexpr size_t OFF_XB   = 0;
static constexpr size_t OFF_WQKV = 16777216;
static constexpr size_t OFF_KH   = 16777216;
static constexpr size_t OFF_VT   = 20971520;
static constexpr size_t OFF_ML   = 25165824;
static constexpr size_t OFF_WP   = 29360128;
static constexpr size_t OFF_QKV  = 37748736;
static constexpr size_t OFF_Y    = 79691776;

__device__ __forceinline__ u16 f2bf(float f) {
  union { float f; unsigned u; } v; v.f = f;
  unsigned r = v.u + 0x7fffu + ((v.u >> 16) & 1u);   // RNE
  return (u16)(r >> 16);
}

__device__ __forceinline__ float bf2f(u16 b) {
  union { unsigned u; float f; } v; v.u = ((unsigned)b) << 16;
  return v.f;
}

__device__ __forceinline__ void async16(const u16* g, u16* lds) {
  __builtin_amdgcn_global_load_lds(
      (const __attribute__((address_space(1))) void*)g,
      (__attribute__((address_space(3))) void*)lds, 16, 0, 0);
}

// ---------------- bitlinear weight quantization ----------------
__global__ __launch_bounds__(256) void quant_rows(const float* __restrict__ W,
                                                  u16* __restrict__ out) {
  const int row = blockIdx.x, tid = threadIdx.x;
  const float* src = W + (size_t)row * 2048 + tid * 8;
  float4 a = *(const float4*)(src);
  float4 b = *(const float4*)(src + 4);
  float asum = fabsf(a.x)+fabsf(a.y)+fabsf(a.z)+fabsf(a.w)
             + fabsf(b.x)+fabsf(b.y)+fabsf(b.z)+fabsf(b.w);
  #pragma unroll
  for (int off = 1; off < 64; off <<= 1) asum += __shfl_xor(asum, off, 64);
  __shared__ float red[4];
  if ((tid & 63) == 0) red[tid >> 6] = asum;
  __syncthreads();
  float s = fmaxf((red[0]+red[1]+red[2]+red[3]) * (1.0f/2048.0f), 1e-5f);
  float v[8] = {a.x,a.y,a.z,a.w,b.x,b.y,b.z,b.w};
  u16* dst = out + (size_t)row * 2048 + tid * 8;
  #pragma unroll
  for (int i = 0; i < 8; i++) {
    float q = rintf(v[i] / s);
    q = fminf(fmaxf(q, -1.f), 1.f);
    dst[i] = f2bf(q * s);
  }
}

// ---------------- fp32 -> bf16 ----------------
__global__ __launch_bounds__(256) void cvt_bf16(const float* __restrict__ in,
                                                u16* __restrict__ out) {
  size_t i = ((size_t)blockIdx.x * 256 + threadIdx.x) * 4;
  float4 v = *(const float4*)(in + i);
  u16x4 o;
  o.x = f2bf(v.x); o.y = f2bf(v.y); o.z = f2bf(v.z); o.w = f2bf(v.w);
  *(u16x4*)(out + i) = o;
}

// ---------------- GEMM  C[M][N] = A[M][K] * B[N][K]^T  (bf16 in, fp32 out) -------
__global__ __launch_bounds__(256) void gemm_bt(const u16* __restrict__ A,
                                               const u16* __restrict__ B,
                                               float* __restrict__ C,
                                               int M, int N, int K) {
  __shared__ u16 sA[128 * 32];
  __shared__ u16 sB[128 * 32];
  const int tid = threadIdx.x;
  const int lane = tid & 63;
  const int wid = tid >> 6;
  const int lr = lane & 15, lq = lane >> 4;
  const int wm = (wid >> 1) * 64, wn = (wid & 1) * 64;
  const size_t m0 = (size_t)blockIdx.y * 128, n0 = (size_t)blockIdx.x * 128;

  const int r0 = tid >> 2, c0 = (tid & 3) * 8;
  const u16* Ab0 = A + (m0 + r0) * (size_t)K + c0;
  const u16* Ab1 = A + (m0 + 64 + r0) * (size_t)K + c0;
  const u16* Bb0 = B + (n0 + r0) * (size_t)K + c0;
  const u16* Bb1 = B + (n0 + 64 + r0) * (size_t)K + c0;
  u16* sA0 = &sA[tid * 8];
  u16* sA1 = &sA[(256 + tid) * 8];
  u16* sB0 = &sB[tid * 8];
  u16* sB1 = &sB[(256 + tid) * 8];

  f32x4 acc[4][4] = {};

  for (int kt = 0; kt < K; kt += 32) {
    async16(Ab0 + kt, sA0);
    async16(Ab1 + kt, sA1);
    async16(Bb0 + kt, sB0);
    async16(Bb1 + kt, sB1);
    __syncthreads();
    s16x8 af[4], bf[4];
    #pragma unroll
    for (int mt = 0; mt < 4; mt++)
      af[mt] = *(const s16x8*)&sA[(wm + mt * 16 + lr) * 32 + lq * 8];
    #pragma unroll
    for (int nt = 0; nt < 4; nt++)
      bf[nt] = *(const s16x8*)&sB[(wn + nt * 16 + lr) * 32 + lq * 8];
    #pragma unroll
    for (int mt = 0; mt < 4; mt++)
      #pragma unroll
      for (int nt = 0; nt < 4; nt++)
        acc[mt][nt] = __builtin_amdgcn_mfma_f32_16x16x32_bf16(af[mt], bf[nt], acc[mt][nt], 0, 0, 0);
    __syncthreads();
  }
  #pragma unroll
  for (int mt = 0; mt < 4; mt++)
    #pragma unroll
    for (int nt = 0; nt < 4; nt++)
      #pragma unroll
      for (int r = 0; r < 4; r++) {
        size_t m = m0 + wm + mt * 16 + lq * 4 + r;
        size_t n = n0 + wn + nt * 16 + lr;
        C[m * (size_t)N + n] = acc[mt][nt][r];
      }
}

// ---------------- rmsnorm + rope (+gain+scale for Q) ----------------
__global__ __launch_bounds__(256) void prep_qk(const float* __restrict__ qkv,
                                               const float* __restrict__ qgain,
                                               u16* __restrict__ Qh,
                                               u16* __restrict__ Kh) {
  const int s = blockIdx.y;
  const int j = blockIdx.x * 4 + (threadIdx.x >> 6);
  const int t = threadIdx.x & 63;
  const float* row = qkv + (size_t)s * 3072 + (size_t)j * 128;
  float x1 = row[t], x2 = row[t + 64];
  float ss = x1 * x1 + x2 * x2;
  #pragma unroll
  for (int off = 1; off < 64; off <<= 1) ss += __shfl_xor(ss, off, 64);
  float rn = rsqrtf(ss * (1.0f / 128.0f) + 1.1920929e-07f);
  float invf = exp2f(-(float)t * 0.20762050593048096f);  // log2(10000)/64
  float ang = (float)s * invf;
  float sn, c;
  sincosf(ang, &sn, &c);
  if (j < 16) {
    float g = qgain[j] * 0.12751738f;   // (1/sqrt(128)) * log2(e)
    float q1 = x1 * rn, q2 = x2 * rn;
    float o1 = (q1 * c + q2 * sn) * g;
    float o2 = (-q1 * sn + q2 * c) * g;
    u16* dst = Qh + ((size_t)j * 4096 + s) * 128;
    dst[t] = f2bf(o1); dst[t + 64] = f2bf(o2);
  } else {
    float k1 = x1 * rn, k2 = x2 * rn;
    float o1 = k1 * c + k2 * sn;
    float o2 = -k1 * sn + k2 * c;
    u16* dst = Kh + ((size_t)(j - 16) * 4096 + s) * 128;
    dst[t] = f2bf(o1); dst[t + 64] = f2bf(o2);
  }
}

// ---------------- V transpose ----------------
__global__ __launch_bounds__(256) void vtrans(const float* __restrict__ qkv,
                                              u16* __restrict__ Vtg) {
  __shared__ float tile[64][67];
  const int tid = threadIdx.x;
  const int s0 = blockIdx.y * 64;
  const int c0 = blockIdx.x * 64;
  #pragma unroll
  for (int it = 0; it < 4; it++) {
    int i = it * 256 + tid;
    int r = i >> 4, c = (i & 15) * 4;
    float4 v = *(const float4*)(qkv + (size_t)(s0 + r) * 3072 + 2560 + c0 + c);
    tile[r][c] = v.x; tile[r][c + 1] = v.y; tile[r][c + 2] = v.z; tile[r][c + 3] = v.w;
  }
  __syncthreads();
  #pragma unroll
  for (int it = 0; it < 2; it++) {
    int i = it * 256 + tid;
    int dl = i >> 3, sc = (i & 7) * 8;
    s16x8 ov;
    #pragma unroll
    for (int jj = 0; jj < 8; jj++) ov[jj] = (short)f2bf(tile[sc + jj][dl]);
    *(s16x8*)&Vtg[(size_t)(c0 + dl) * 4096 + s0 + sc] = ov;
  }
}

// ---------------- flash attention v5: uniform 16/17-step units ---------------
// Grid 1024 = 64 units x 16 heads; every unit = 16-17 kv-tile steps (perfect
// balance, all co-resident). Unit = up to 2 static segments (qt, kv0, kv1,
// slot); slot 127 = tile fully covered -> direct Y; else bf16 O-partial +
// fp32 (m,l) into one of 79 slots/head. Static geometry tables below.
#define SEG(qt,a,b,s) ((unsigned)((qt)|((a)<<5)|((b)<<11)|((s)<<18)))
__constant__ unsigned SEGTAB[128] = {
  SEG(0,0,2,127),   SEG(15,0,15,14),  // u0
  SEG(15,15,32,15), 0,                // u1
  SEG(1,0,4,127),   SEG(14,0,13,12),
  SEG(14,13,30,13), 0,
  SEG(2,0,6,127),   SEG(13,0,11,10),
  SEG(13,11,28,11), 0,
  SEG(3,0,8,127),   SEG(12,0,9,8),
  SEG(12,9,26,9),   0,
  SEG(4,0,10,127),  SEG(11,0,7,6),
  SEG(11,7,24,7),   0,
  SEG(5,0,12,127),  SEG(10,0,5,4),
  SEG(10,5,22,5),   0,
  SEG(6,0,14,127),  SEG(9,0,3,2),
  SEG(9,3,20,3),    0,
  SEG(7,0,16,127),  SEG(8,0,1,0),
  SEG(8,1,18,1),    0,
  SEG(16,0,16,16),  0,                // u16 (phase 2)
  SEG(16,16,33,17), 0,
  SEG(16,33,34,18), SEG(17,0,15,19),
  SEG(17,15,31,20), 0,
  SEG(17,31,36,21), SEG(18,0,12,22),
  SEG(18,12,28,23), 0,
  SEG(18,28,38,24), SEG(19,0,6,25),
  SEG(19,6,23,26),  0,
  SEG(19,23,39,27), 0,
  SEG(19,39,40,28), SEG(20,0,15,29),
  SEG(20,15,32,30), 0,
  SEG(20,32,42,31), SEG(21,0,6,32),
  SEG(21,6,22,33),  0,
  SEG(21,22,39,34), 0,
  SEG(21,39,44,35), SEG(22,0,11,36),
  SEG(22,11,27,37), 0,
  SEG(22,27,44,38), 0,
  SEG(22,44,46,39), SEG(23,0,14,40),
  SEG(23,14,30,41), 0,
  SEG(23,30,47,42), 0,
  SEG(23,47,48,43), SEG(24,0,15,44),
  SEG(24,15,31,45), 0,
  SEG(24,31,48,46), 0,
  SEG(24,48,50,47), SEG(25,0,14,48),
  SEG(25,14,30,49), 0,
  SEG(25,30,47,50), 0,
  SEG(25,47,52,51), SEG(26,0,11,52),
  SEG(26,11,27,53), 0,
  SEG(26,27,44,54), 0,
  SEG(26,44,54,55), SEG(27,0,6,56),
  SEG(27,6,22,57),  0,
  SEG(27,22,39,58), 0,
  SEG(27,39,55,59), 0,
  SEG(27,55,56,60), SEG(28,0,15,61),
  SEG(28,15,32,62), 0,
  SEG(28,32,48,63), 0,
  SEG(28,48,58,64), SEG(29,0,6,65),
  SEG(29,6,23,66),  0,
  SEG(29,23,39,67), 0,
  SEG(29,39,55,68), 0,
  SEG(29,55,60,69), SEG(30,0,12,70),
  SEG(30,12,28,71), 0,
  SEG(30,28,44,72), 0,
  SEG(30,44,61,73), 0,
  SEG(30,61,62,74), SEG(31,0,15,75),
  SEG(31,15,31,76), 0,
  SEG(31,31,48,77), 0,
  SEG(31,48,64,78), 0,
};
// combine: per tile qt in [8,31]: partial slot base and count
__constant__ unsigned char CBASE[24] = {0,2,4,6,8,10,12,14, 16,19,22,25,29,32,36,40, 44,48,52,56,61,65,70,75};
__constant__ unsigned char CCNT[24]  = {2,2,2,2,2,2,2,2, 3,3,3,4,3,4,4,4, 4,4,4,5,4,5,5,4};

__global__ __launch_bounds__(256, 2) void attn(const u16* __restrict__ Q,
                                               const u16* __restrict__ Kh,
                                               const u16* __restrict__ Vt,
                                               u16* __restrict__ Y,
                                               u16* __restrict__ Opart,
                                               float* __restrict__ MLpart) {
  const int tid = threadIdx.x, lane = tid & 63, wid = tid >> 6;
  const int lr = lane & 15, lq = lane >> 4;
  const int b = blockIdx.x;
  const int h = b & 15, unit = b >> 4;
  const int kvh = h >> 2;

  __shared__ u16 sK[64][136];
  __shared__ u16 sVt[128][72];

  const u16* Kbase = Kh + (size_t)kvh * 4096 * 128;
  const u16* Vbase = Vt + (size_t)kvh * 128 * 4096;

  #pragma unroll 1
  for (int si = 0; si < 2; ++si) {
    const unsigned sd = SEGTAB[unit * 2 + si];
    const int qt = sd & 31;
    const int t0 = (sd >> 5) & 63;
    const int t1 = (sd >> 11) & 127;
    const int slot = (sd >> 18) & 127;
    if (t1 <= t0) continue;
    const int qbase = qt * 128;

    s16x8 qf[2][4];
    #pragma unroll
    for (int f = 0; f < 2; f++) {
      const u16* qp = Q + ((size_t)h * 4096 + qbase + wid * 32 + f * 16 + lr) * 128 + lq * 8;
      #pragma unroll
      for (int kc = 0; kc < 4; kc++) qf[f][kc] = *(const s16x8*)(qp + kc * 32);
    }

    f32x4 oacc[2][8] = {};
    float mrow[2] = {-1e30f, -1e30f};
    float lrow[2] = {0.f, 0.f};

    for (int t = t0; t < t1; ++t) {
      #pragma unroll
      for (int it = 0; it < 4; it++) {
        int idx = it * 256 + tid;
        int kr = idx >> 4, kc8 = (idx & 15) * 8;
        *(s16x8*)&sK[kr][kc8] = *(const s16x8*)(Kbase + (size_t)(t * 64 + kr) * 128 + kc8);
      }
      #pragma unroll
      for (int it = 0; it < 4; it++) {
        int idx = it * 256 + tid;
        int vd = idx >> 3, vc = (idx & 7) * 8;
        s16x8 v = *(const s16x8*)(Vbase + (size_t)vd * 4096 + t * 64 + vc);
        int g0 = ((vc >> 2) & 3) * 16 + (vc >> 4) * 4;
        int g1 = (((vc >> 2) & 3) + 1) * 16 + (vc >> 4) * 4;
        s16x4 lo = {v[0], v[1], v[2], v[3]};
        s16x4 hi = {v[4], v[5], v[6], v[7]};
        *(s16x4*)&sVt[vd][g0] = lo;
        *(s16x4*)&sVt[vd][g1] = hi;
      }
      __syncthreads();

      // S^T = K · Q^T
      f32x4 sacc[2][4] = {};
      #pragma unroll
      for (int nt = 0; nt < 4; nt++)
        #pragma unroll
        for (int kc = 0; kc < 4; kc++) {
          s16x8 kf = *(const s16x8*)&sK[nt * 16 + lr][kc * 32 + lq * 8];
          sacc[0][nt] = __builtin_amdgcn_mfma_f32_16x16x32_bf16(kf, qf[0][kc], sacc[0][nt], 0, 0, 0);
          sacc[1][nt] = __builtin_amdgcn_mfma_f32_16x16x32_bf16(kf, qf[1][kc], sacc[1][nt], 0, 0, 0);
        }

      if (t >= 2 * qt) {   // causal mask: kv > q
        #pragma unroll
        for (int f = 0; f < 2; f++) {
          int qg = qbase + wid * 32 + f * 16 + lr;
          #pragma unroll
          for (int nt = 0; nt < 4; nt++) {
            int kv0 = t * 64 + nt * 16 + lq * 4;
            #pragma unroll
            for (int r = 0; r < 4; r++)
              if (kv0 + r > qg) sacc[f][nt][r] = -1e30f;
          }
        }
      }

      float mx[2];
      #pragma unroll
      for (int f = 0; f < 2; f++) {
        float m01 = fmaxf(fmaxf(sacc[f][0][0], sacc[f][0][1]), fmaxf(sacc[f][0][2], sacc[f][0][3]));
        float m23 = fmaxf(fmaxf(sacc[f][1][0], sacc[f][1][1]), fmaxf(sacc[f][1][2], sacc[f][1][3]));
        float m45 = fmaxf(fmaxf(sacc[f][2][0], sacc[f][2][1]), fmaxf(sacc[f][2][2], sacc[f][2][3]));
        float m67 = fmaxf(fmaxf(sacc[f][3][0], sacc[f][3][1]), fmaxf(sacc[f][3][2], sacc[f][3][3]));
        mx[f] = fmaxf(fmaxf(m01, m23), fmaxf(m45, m67));
        mx[f] = fmaxf(mx[f], __shfl_xor(mx[f], 16, 64));
        mx[f] = fmaxf(mx[f], __shfl_xor(mx[f], 32, 64));
      }

      bool grow = (mx[0] > mrow[0]) || (mx[1] > mrow[1]);
      if (__any(grow)) {
        #pragma unroll
        for (int f = 0; f < 2; f++) {
          float mn = fmaxf(mrow[f], mx[f]);
          float al = exp2f(mrow[f] - mn);
          mrow[f] = mn;
          lrow[f] *= al;
          #pragma unroll
          for (int dt = 0; dt < 8; dt++)
            #pragma unroll
            for (int r = 0; r < 4; r++) oacc[f][dt][r] *= al;
        }
      }

      s16x4 pf[2][4];
      float rsum[2] = {0.f, 0.f};
      #pragma unroll
      for (int f = 0; f < 2; f++)
        #pragma unroll
        for (int nt = 0; nt < 4; nt++)
          #pragma unroll
          for (int r = 0; r < 4; r++) {
            union { float fv; unsigned u; } pu;
            pu.fv = exp2f(sacc[f][nt][r] - mrow[f]);
            rsum[f] += pu.fv;
            pf[f][nt][r] = (short)(pu.u >> 16);
          }
      #pragma unroll
      for (int f = 0; f < 2; f++) {
        rsum[f] += __shfl_xor(rsum[f], 16, 64);
        rsum[f] += __shfl_xor(rsum[f], 32, 64);
        lrow[f] += rsum[f];
      }

      // O^T += V^T · P^T  (16x16x16)
      #pragma unroll
      for (int dt = 0; dt < 8; dt++) {
        s16x8 v01 = *(const s16x8*)&sVt[dt * 16 + lr][lq * 16];
        s16x8 v23 = *(const s16x8*)&sVt[dt * 16 + lr][lq * 16 + 8];
        s16x4 vf0 = {v01[0], v01[1], v01[2], v01[3]};
        s16x4 vf1 = {v01[4], v01[5], v01[6], v01[7]};
        s16x4 vf2 = {v23[0], v23[1], v23[2], v23[3]};
        s16x4 vf3 = {v23[4], v23[5], v23[6], v23[7]};
        #pragma unroll
        for (int f = 0; f < 2; f++) {
          oacc[f][dt] = __builtin_amdgcn_mfma_f32_16x16x16bf16_1k(vf0, pf[f][0], oacc[f][dt], 0, 0, 0);
          oacc[f][dt] = __builtin_amdgcn_mfma_f32_16x16x16bf16_1k(vf1, pf[f][1], oacc[f][dt], 0, 0, 0);
          oacc[f][dt] = __builtin_amdgcn_mfma_f32_16x16x16bf16_1k(vf2, pf[f][2], oacc[f][dt], 0, 0, 0);
          oacc[f][dt] = __builtin_amdgcn_mfma_f32_16x16x16bf16_1k(vf3, pf[f][3], oacc[f][dt], 0, 0, 0);
        }
      }
      __syncthreads();
    }

    // epilogue: lane layout q = wid*32 + f*16 + lr, d = dt*16 + lq*4 + r
    if (slot == 127) {
      #pragma unroll
      for (int f = 0; f < 2; f++) {
        float linv = 1.0f / lrow[f];
        int qg = qbase + wid * 32 + f * 16 + lr;
        #pragma unroll
        for (int dt = 0; dt < 8; dt++) {
          u16 tmp[4];
          #pragma unroll
          for (int r = 0; r < 4; r++) tmp[r] = f2bf(oacc[f][dt][r] * linv);
          *(s16x4*)&Y[(size_t)qg * 2048 + h * 128 + dt * 16 + lq * 4] = *(s16x4*)tmp;
        }
      }
    } else {
      const int gslot = h * 79 + slot;
      u16* Op = Opart + (size_t)gslot * 16384;
      #pragma unroll
      for (int f = 0; f < 2; f++) {
        int row = wid * 32 + f * 16 + lr;
        #pragma unroll
        for (int dt = 0; dt < 8; dt++) {
          u16 tmp[4];
          #pragma unroll
          for (int r = 0; r < 4; r++) tmp[r] = f2bf(oacc[f][dt][r]);
          *(s16x4*)&Op[row * 128 + dt * 16 + lq * 4] = *(s16x4*)tmp;
        }
        if (lq == 0) {
          MLpart[(size_t)gslot * 256 + row * 2]     = mrow[f];
          MLpart[(size_t)gslot * 256 + row * 2 + 1] = lrow[f];
        }
      }
    }
  }
}

// ---------------- combine: merge 2-5 partials per split tile -> Y ----------
__global__ __launch_bounds__(256) void combine(const u16* __restrict__ Op,
                                               const float* __restrict__ ML,
                                               u16* __restrict__ Y) {
  const int b = blockIdx.x;
  const int qt = 8 + (b >> 4), h = b & 15;
  const int base = CBASE[qt - 8], n = CCNT[qt - 8];
  const int gbase = h * 79 + base;
  const int tid = threadIdx.x;
  const int row = tid >> 1, half = (tid & 1) * 64;

  float m[5], l[5];
  float mstar = -3e38f;
  for (int i = 0; i < n; i++) {
    m[i] = ML[(size_t)(gbase + i) * 256 + row * 2];
    l[i] = ML[(size_t)(gbase + i) * 256 + row * 2 + 1];
    mstar = fmaxf(mstar, m[i]);
  }
  float w[5], wsum = 0.f;
  for (int i = 0; i < n; i++) { w[i] = exp2f(m[i] - mstar); wsum += l[i] * w[i]; }
  float inv = 1.0f / wsum;

  float acc[64] = {};
  for (int i = 0; i < n; i++) {
    const u16* o = Op + (size_t)(gbase + i) * 16384 + row * 128 + half;
    float wi = w[i];
    #pragma unroll
    for (int c = 0; c < 64; c += 8) {
      s16x8 a = *(const s16x8*)(o + c);
      #pragma unroll
      for (int jj = 0; jj < 8; jj++) acc[c + jj] += wi * bf2f((u16)a[jj]);
    }
  }
  u16* dst = Y + ((size_t)qt * 128 + row) * 2048 + h * 128 + half;
  #pragma unroll
  for (int c = 0; c < 64; c += 8) {
    u16 tmp[8];
    #pragma unroll
    for (int jj = 0; jj < 8; jj++) tmp[jj] = f2bf(acc[c + jj] * inv);
    *(s16x8*)(dst + c) = *(s16x8*)tmp;
  }
}

// ---------------- launch ----------------
extern "C" void kernel_launch(void* const* d_in, const int* in_sizes, int n_in,
                              void* d_out, int out_size, void* d_ws, size_t ws_size,
                              hipStream_t stream) {
  const float* x  = (const float*)d_in[0];
  const float* wq = (const float*)d_in[1];
  const float* wk = (const float*)d_in[2];
  const float* wv = (const float*)d_in[3];
  const float* wp = (const float*)d_in[4];
  const float* qg = (const float*)d_in[5];
  float* out = (float*)d_out;
  char* ws = (char*)d_ws;

  u16*   XB    = (u16*)(ws + OFF_XB);
  u16*   WQKV  = (u16*)(ws + OFF_WQKV);
  u16*   WP    = (u16*)(ws + OFF_WP);
  float* QKV   = (float*)(ws + OFF_QKV);
  u16*   QH    = XB;                      // reuse after GEMM1
  u16*   KH    = (u16*)(ws + OFF_KH);     // reuse of WQKV region after GEMM1
  u16*   VT    = (u16*)(ws + OFF_VT);
  float* MLP   = (float*)(ws + OFF_ML);
  u16*   OPART = (u16*)(ws + OFF_QKV);    // reuse after prep/vtrans
  u16*   Yb    = (u16*)(ws + OFF_Y);

  quant_rows<<<2048, 256, 0, stream>>>(wq, WQKV);
  quant_rows<<<512,  256, 0, stream>>>(wk, WQKV + (size_t)2048 * 2048);
  quant_rows<<<512,  256, 0, stream>>>(wv, WQKV + (size_t)2560 * 2048);
  quant_rows<<<2048, 256, 0, stream>>>(wp, WP);
  cvt_bf16<<<8192, 256, 0, stream>>>(x, XB);
  gemm_bt<<<dim3(24, 32), 256, 0, stream>>>(XB, WQKV, QKV, 4096, 3072, 2048);
  prep_qk<<<dim3(5, 4096), 256, 0, stream>>>(QKV, qg, QH, KH);
  vtrans<<<dim3(8, 64), 256, 0, stream>>>(QKV, VT);
  attn<<<1024, 256, 0, stream>>>(QH, KH, VT, Yb, OPART, MLP);
  combine<<<384, 256, 0, stream>>>(OPART, MLP, Yb);
  gemm_bt<<<dim3(16, 32), 256, 0, stream>>>(Yb, WP, out, 4096, 2048, 2048);
}